// Round 8
// baseline (322.305 us; speedup 1.0000x reference)
//
#include <hip/hip_runtime.h>
#include <hip/hip_fp16.h>

#define N_NODES 50000
#define N_EDGES 640000
#define HIDDEN  128
#define N_LAYERS 4
#define TILE_E  128
#define EBLK    (N_EDGES / TILE_E)   // 5000
#define NCHUNK  196                  // ceil(50000/256)
#define NBLK64  ((N_NODES + 63) / 64)  // 782

#define OUT_GHOST  (N_NODES * HIDDEN)
#define OUT_PERIOD (OUT_GHOST + N_NODES)
#define OUT_GRAD   (OUT_PERIOD + N_NODES)

typedef _Float16 f16x8 __attribute__((ext_vector_type(8)));
typedef _Float16 f16x2 __attribute__((ext_vector_type(2)));
typedef float    f32x4 __attribute__((ext_vector_type(4)));

// LDS tile: rows x 256 bytes, XOR-swizzled (T2): byte ^= ((row&7)<<4).
__device__ __forceinline__ int swz(int row, int colbyte) {
    return (row * 256 + colbyte) ^ ((row & 7) << 4);
}

// ---- edge_index dtype self-detection (int64 LE with ids<2^31 -> odd words 0) ----
__device__ __forceinline__ int ei_is64(const int* __restrict__ ei) {
    return (ei[1] == 0 && ei[3] == 0 && ei[5] == 0) ? 1 : 0;
}
__device__ __forceinline__ int ei_src(const int* __restrict__ ei, int is64, int e) {
    return is64 ? ei[2 * e] : ei[e];
}
__device__ __forceinline__ int ei_dst(const int* __restrict__ ei, int is64, int e) {
    return is64 ? ei[2 * (N_EDGES + e)] : ei[N_EDGES + e];
}

// ---------------- CSR build ----------------
__global__ void count_kernel(const int* __restrict__ ei, int* __restrict__ counts) {
    int e = blockIdx.x * 256 + threadIdx.x;
    atomicAdd(&counts[ei_dst(ei, ei_is64(ei), e)], 1);
}

// per-chunk local exclusive scan of counts -> cursor, chunk totals -> chunkSum;
// also per-call node init (bslot=-1, zero deg-0 aggH rows).
__global__ void csr_local_kernel(const int* __restrict__ counts, int* __restrict__ cursor,
                                 int* __restrict__ chunkSum, int* __restrict__ bslot,
                                 _Float16* __restrict__ aggH) {
    __shared__ int buf[256];
    int t = threadIdx.x, i = blockIdx.x * 256 + t;
    int v = (i < N_NODES) ? counts[i] : 0;
    buf[t] = v;
    __syncthreads();
    for (int off = 1; off < 256; off <<= 1) {
        int add = (t >= off) ? buf[t - off] : 0;
        __syncthreads();
        buf[t] += add;
        __syncthreads();
    }
    if (i < N_NODES) {
        cursor[i] = buf[t] - v;   // chunk-local exclusive prefix
        bslot[i] = -1;
        if (v == 0) {
            float4 z = {0.f, 0.f, 0.f, 0.f};
#pragma unroll
            for (int k = 0; k < 16; ++k)
                *(float4*)&aggH[(size_t)i * 128 + k * 8] = z;
        }
    }
    if (t == 255) chunkSum[blockIdx.x] = buf[255];
}

__global__ void chunk_scan_kernel(const int* __restrict__ chunkSum, int* __restrict__ chunkBase) {
    __shared__ int buf[256];
    int t = threadIdx.x;
    int v = (t < NCHUNK) ? chunkSum[t] : 0;
    buf[t] = v;
    __syncthreads();
    for (int off = 1; off < 256; off <<= 1) {
        int add = (t >= off) ? buf[t - off] : 0;
        __syncthreads();
        buf[t] += add;
        __syncthreads();
    }
    if (t < NCHUNK) chunkBase[t] = buf[t] - v;
}

// rank-scatter into ONE packed 8B stream: {src16|dst16, ea_f32}
__global__ void scatter_kernel(const int* __restrict__ ei, const float* __restrict__ ea,
                               const int* __restrict__ chunkBase, int* __restrict__ cursor,
                               uint2* __restrict__ sdPE) {
    int e = blockIdx.x * 256 + threadIdx.x;
    int is64 = ei_is64(ei);
    int s = ei_src(ei, is64, e);
    int d = ei_dst(ei, is64, e);
    int p = chunkBase[d >> 8] + atomicAdd(&cursor[d], 1);
    uint2 v;
    v.x = (unsigned)s | ((unsigned)d << 16);   // N_NODES < 65536
    v.y = __float_as_uint(ea[e]);
    sdPE[p] = v;
}

// ---------------- weight pre-pack into MFMA fragment order (f16) ----------------
__global__ void pack_w_kernel(const float* __restrict__ W1, const float* __restrict__ W2,
                              _Float16* __restrict__ W1c, _Float16* __restrict__ W2p) {
    int id = blockIdx.x * 256 + threadIdx.x;
    if (id < 131072) {
        int j = id & 7, l = (id >> 3) & 63, c = (id >> 9) & 15, kb = (id >> 13) & 3, lay = id >> 15;
        int k = kb * 32 + (l >> 4) * 8 + j, col = c * 16 + (l & 15);
        const float* Wl = W1 + (size_t)lay * 257 * 128;
        W1c[id] = (_Float16)((col < 128) ? Wl[(size_t)k * 128 + col]
                                         : Wl[(size_t)(128 + k) * 128 + (col - 128)]);
    } else if (id < 196608) {
        int id2 = id - 131072;
        int j = id2 & 7, l = (id2 >> 3) & 63, c = (id2 >> 9) & 7, kb = (id2 >> 12) & 3, lay = id2 >> 14;
        int k = kb * 32 + (l >> 4) * 8 + j, col = c * 16 + (l & 15);
        W2p[id2] = (_Float16)W2[(size_t)lay * 128 * 128 + (size_t)k * 128 + col];
    }
}

// ---------------- boundary slots (valid while max degree < TILE_E) ----------------
__global__ void bnd_setup_kernel(const uint2* __restrict__ sdPE, int* __restrict__ bslot) {
    int t = blockIdx.x * 256 + threadIdx.x;
    if (t >= 1 && t < EBLK) {
        unsigned dp = sdPE[t * TILE_E - 1].x >> 16;
        unsigned d0 = sdPE[t * TILE_E].x >> 16;
        if (dp == d0) bslot[d0] = t;
    }
}

// ---------------- edge kernel: gather P'[dst]+Q[src] -> hidden -> segment-sum ----------------
// P' has b1 pre-folded; hidden = relu(P' + Q + ea*w1last). Gathers issue pre-barrier.
__global__ __launch_bounds__(512, 8)
void edge_gather_kernel(const _Float16* __restrict__ PQ,
                        const uint2* __restrict__ sdPE,
                        const float* __restrict__ w1last,
                        _Float16* __restrict__ aggH, float* __restrict__ agg32c) {
    __shared__ __align__(16) unsigned char tile[TILE_E * 256];
    __shared__ int dstL[TILE_E];
    __shared__ int segStart[TILE_E + 1];
    __shared__ int nsegS, contP, contN;

    const int tid = threadIdx.x;
    const int bid = (blockIdx.x & 7) * (EBLK / 8) + (blockIdx.x >> 3);  // XCD swizzle
    const int e_base = bid * TILE_E;

    // P0a: per-thread packed loads for own gather rows (broadcast within t16 group),
    // issue all 8 P/Q gathers immediately — before any barrier.
    const int t16 = tid & 15, rg = tid >> 4;
    const int c8 = t16 * 8;
    uint2 sd[4];
#pragma unroll
    for (int rr = 0; rr < 4; ++rr) sd[rr] = sdPE[e_base + rg + 32 * rr];

    f16x8 pv[4], qv[4];
#pragma unroll
    for (int rr = 0; rr < 4; ++rr) {
        int s = (int)(sd[rr].x & 0xFFFFu);
        int d = (int)(sd[rr].x >> 16);
        pv[rr] = *(const f16x8*)&PQ[(size_t)d * 256 + c8];
        qv[rr] = *(const f16x8*)&PQ[(size_t)s * 256 + 128 + c8];
    }

    // P0b: stage dstL + continuation flags (runs under the in-flight gathers)
    if (tid < TILE_E) {
        dstL[tid] = (int)(sdPE[e_base + tid].x >> 16);   // L1-hot second read
    } else if (tid == TILE_E) {
        contP = (e_base > 0 && (sdPE[e_base - 1].x >> 16) == (sdPE[e_base].x >> 16)) ? 1 : 0;
    } else if (tid == TILE_E + 1) {
        contN = (e_base + TILE_E < N_EDGES &&
                 (sdPE[e_base + TILE_E - 1].x >> 16) == (sdPE[e_base + TILE_E].x >> 16)) ? 1 : 0;
    }
    __syncthreads();

    // segment ranks (waves 0,1) — concurrent with P1's VALU below in other waves
    if (tid < 128) {
        int lane = tid & 63;
        int fl_lo = (lane == 0) ? 1 : (dstL[lane] != dstL[lane - 1]);
        unsigned long long m0 = __ballot(fl_lo);
        if (tid < 64) {
            if (fl_lo) segStart[__popcll(m0 & ((1ull << lane) - 1))] = lane;
        } else {
            int j = 64 + lane;
            int fl = (dstL[j] != dstL[j - 1]);
            unsigned long long m1 = __ballot(fl);
            int nlo = __popcll(m0);
            if (fl) segStart[nlo + __popcll(m1 & ((1ull << lane) - 1))] = j;
            if (lane == 0) {
                int ns = nlo + __popcll(m1);
                nsegS = ns;
                segStart[ns] = TILE_E;
            }
        }
    }

    // P1: packed-f16 hidden = relu(P' + Q + ea*wl) -> tile
    {
        f16x8 wl8, z8;
#pragma unroll
        for (int j = 0; j < 8; ++j) {
            wl8[j] = (_Float16)w1last[c8 + j];
            z8[j]  = (_Float16)0.f;
        }
#pragma unroll
        for (int rr = 0; rr < 4; ++rr) {
            int row = rg + 32 * rr;
            _Float16 ea16 = (_Float16)__uint_as_float(sd[rr].y);
            f16x8 t = pv[rr] + qv[rr] + wl8 * ea16;
            f16x8 hv = __builtin_elementwise_max(t, z8);
            *(f16x8*)(tile + swz(row, c8 * 2)) = hv;
        }
    }
    __syncthreads();

    // P2: per-segment column sums; interior -> f16 store, boundary -> slot atomics
    {
        int col2 = (tid & 63) * 2, sh = tid >> 6;
        int ns = nsegS, cP = contP, cN = contN;
        for (int s = sh; s < ns; s += 8) {
            int b = segStart[s], en = segStart[s + 1];
            float s0 = 0.f, s1 = 0.f;
            for (int e2 = b; e2 < en; ++e2) {
                f16x2 hv = *(const f16x2*)(tile + swz(e2, col2 * 2));
                s0 += (float)hv[0];
                s1 += (float)hv[1];
            }
            bool isP = (s == 0 && cP), isN = (s == ns - 1 && cN);
            if (isP || isN) {
                int slot = isP ? bid : bid + 1;
                atomicAdd(&agg32c[(size_t)slot * 128 + col2], s0);
                atomicAdd(&agg32c[(size_t)slot * 128 + col2 + 1], s1);
            } else {
                int node = dstL[b];
                f16x2 o; o[0] = (_Float16)s0; o[1] = (_Float16)s1;
                *(f16x2*)&aggH[(size_t)node * 128 + col2] = o;
            }
        }
    }
}

// ---------------- node kernel (64 rows/block, 8 waves) ----------------
__global__ __launch_bounds__(512, 6)
void node_layer_kernel(const _Float16* __restrict__ aggH,
                       const int* __restrict__ counts,
                       const int* __restrict__ bslot, float* __restrict__ agg32c,
                       const _Float16* __restrict__ W2p, const float* __restrict__ b2,
                       const _Float16* __restrict__ W1c, const float* __restrict__ b1n,
                       _Float16* __restrict__ PQ, float* __restrict__ out,
                       const float* __restrict__ Wg, const float* __restrict__ bg,
                       const float* __restrict__ Wp, const float* __restrict__ bp,
                       const float* __restrict__ Wr, const float* __restrict__ br,
                       int last) {
    __shared__ __align__(16) unsigned char tile[64 * 256];
    __shared__ int degL[64];
    __shared__ float hw[512];

    const int tid = threadIdx.x;
    const int base = blockIdx.x * 64;

    {
        const int t16 = tid & 15, rg = tid >> 4;
#pragma unroll
        for (int rr = 0; rr < 2; ++rr) {
            int row = rg + 32 * rr;
            int n = base + row;
            f16x8 v = {0, 0, 0, 0, 0, 0, 0, 0};
            if (n < N_NODES) {
                int bs = bslot[n];
                if (bs >= 0) {
                    float* ap = &agg32c[(size_t)bs * 128 + t16 * 8];
                    float4 a = *(const float4*)ap;
                    float4 b = *(const float4*)(ap + 4);
                    v[0] = (_Float16)a.x; v[1] = (_Float16)a.y;
                    v[2] = (_Float16)a.z; v[3] = (_Float16)a.w;
                    v[4] = (_Float16)b.x; v[5] = (_Float16)b.y;
                    v[6] = (_Float16)b.z; v[7] = (_Float16)b.w;
                    float4 z = {0.f, 0.f, 0.f, 0.f};   // re-zero for next layer
                    *(float4*)ap = z; *(float4*)(ap + 4) = z;
                } else {
                    v = *(const f16x8*)&aggH[(size_t)n * 128 + t16 * 8];
                }
            }
            *(f16x8*)(tile + swz(row, t16 * 16)) = v;
        }
        if (tid < 64) degL[tid] = (base + tid < N_NODES) ? counts[base + tid] : 0;
        if (last) {
            if (tid < 128)       hw[tid] = Wg[tid];
            else if (tid < 256)  hw[tid] = Wp[tid - 128];
            else                 hw[tid] = Wr[tid - 256];
        }
    }
    __syncthreads();

    const int w = tid >> 6, l = tid & 63, l16 = l & 15, lg = l >> 4;

    // GEMM_h: wave w -> h cols [16w, 16w+16)
    f32x4 acc[4];
#pragma unroll
    for (int rt = 0; rt < 4; ++rt) acc[rt] = (f32x4){0.f, 0.f, 0.f, 0.f};
    const f16x8* W2v = (const f16x8*)W2p;
#pragma unroll
    for (int kb = 0; kb < 4; ++kb) {
        f16x8 bf = W2v[(kb * 8 + w) * 64 + l];
#pragma unroll
        for (int rt = 0; rt < 4; ++rt) {
            f16x8 a = *(const f16x8*)(tile + swz(rt * 16 + l16, kb * 64 + lg * 16));
            acc[rt] = __builtin_amdgcn_mfma_f32_16x16x32_f16(a, bf, acc[rt], 0, 0, 0);
        }
    }
    __syncthreads();   // all A-reads done before h overwrites tile

    {
        int col = 16 * w + l16;
        float bias = b2[col];
#pragma unroll
        for (int rt = 0; rt < 4; ++rt)
#pragma unroll
            for (int r = 0; r < 4; ++r) {
                int row = rt * 16 + lg * 4 + r;
                float h = fmaxf(acc[rt][r] + (float)degL[row] * bias, 0.f);
                *(_Float16*)(tile + swz(row, col * 2)) = (_Float16)h;
                if (last && base + row < N_NODES)
                    out[(size_t)(base + row) * 128 + col] = h;
            }
    }
    __syncthreads();

    if (last) {
        // fused heads: 8 threads/node, 16 cols each, 3-level shuffle reduce
        int r = tid >> 3, part = tid & 7;
        float sg = 0.f, sp = 0.f, s0 = 0.f, s1 = 0.f;
#pragma unroll
        for (int i = 0; i < 8; ++i) {
            int c = part * 16 + i * 2;
            f16x2 hv = *(const f16x2*)(tile + swz(r, c * 2));
            float h0 = (float)hv[0], h1 = (float)hv[1];
            sg += h0 * hw[c] + h1 * hw[c + 1];
            sp += h0 * hw[128 + c] + h1 * hw[128 + c + 1];
            s0 += h0 * hw[256 + c * 2] + h1 * hw[256 + (c + 1) * 2];
            s1 += h0 * hw[256 + c * 2 + 1] + h1 * hw[256 + (c + 1) * 2 + 1];
        }
        sg += __shfl_xor(sg, 1); sg += __shfl_xor(sg, 2); sg += __shfl_xor(sg, 4);
        sp += __shfl_xor(sp, 1); sp += __shfl_xor(sp, 2); sp += __shfl_xor(sp, 4);
        s0 += __shfl_xor(s0, 1); s0 += __shfl_xor(s0, 2); s0 += __shfl_xor(s0, 4);
        s1 += __shfl_xor(s1, 1); s1 += __shfl_xor(s1, 2); s1 += __shfl_xor(s1, 4);
        int n = base + r;
        if (part == 0 && n < N_NODES) {
            float g = sg + bg[0];
            out[OUT_GHOST + n]        = 1.f / (1.f + expf(-g));
            out[OUT_PERIOD + n]       = sp + bp[0];
            out[OUT_GRAD + n * 2]     = s0 + br[0];
            out[OUT_GRAD + n * 2 + 1] = s1 + br[1];
        }
        return;
    }

    // GEMM_PQ: wave w -> cols [32w, 32w+32) of 256; fold next-layer b1 into P side
    f32x4 acc2[2][4];
#pragma unroll
    for (int ci = 0; ci < 2; ++ci)
#pragma unroll
        for (int rt = 0; rt < 4; ++rt) acc2[ci][rt] = (f32x4){0.f, 0.f, 0.f, 0.f};
    const f16x8* W1v = (const f16x8*)W1c;
#pragma unroll
    for (int kb = 0; kb < 4; ++kb) {
        f16x8 b0  = W1v[(kb * 16 + 2 * w) * 64 + l];
        f16x8 b1f = W1v[(kb * 16 + 2 * w + 1) * 64 + l];
#pragma unroll
        for (int rt = 0; rt < 4; ++rt) {
            f16x8 a = *(const f16x8*)(tile + swz(rt * 16 + l16, kb * 64 + lg * 16));
            acc2[0][rt] = __builtin_amdgcn_mfma_f32_16x16x32_f16(a, b0,  acc2[0][rt], 0, 0, 0);
            acc2[1][rt] = __builtin_amdgcn_mfma_f32_16x16x32_f16(a, b1f, acc2[1][rt], 0, 0, 0);
        }
    }
#pragma unroll
    for (int ci = 0; ci < 2; ++ci) {
        int col = (2 * w + ci) * 16 + l16;
        float bb = (col < 128) ? b1n[col] : 0.f;
#pragma unroll
        for (int rt = 0; rt < 4; ++rt)
#pragma unroll
            for (int r = 0; r < 4; ++r) {
                int row = rt * 16 + lg * 4 + r;
                if (base + row < N_NODES)
                    PQ[(size_t)(base + row) * 256 + col] = (_Float16)(acc2[ci][rt][r] + bb);
            }
    }
}

// ---------------- encoder (64 rows/block) ----------------
__global__ __launch_bounds__(512, 6)
void node_enc_kernel(const float* __restrict__ x,
                     const float* __restrict__ Wenc, const float* __restrict__ benc,
                     const _Float16* __restrict__ W1c, const float* __restrict__ b1n,
                     _Float16* __restrict__ PQ) {
    __shared__ __align__(16) unsigned char tile[64 * 256];
    const int tid = threadIdx.x;
    const int base = blockIdx.x * 64;

    {
        const int t16 = tid & 15, rg = tid >> 4;
        const int c8 = t16 * 8;
        float wv[4][8], bv[8];
#pragma unroll
        for (int i = 0; i < 4; ++i) {
            float4 a = *(const float4*)&Wenc[i * 128 + c8];
            float4 b = *(const float4*)&Wenc[i * 128 + c8 + 4];
            wv[i][0] = a.x; wv[i][1] = a.y; wv[i][2] = a.z; wv[i][3] = a.w;
            wv[i][4] = b.x; wv[i][5] = b.y; wv[i][6] = b.z; wv[i][7] = b.w;
        }
        float4 ba = *(const float4*)&benc[c8];
        float4 bb = *(const float4*)&benc[c8 + 4];
        bv[0] = ba.x; bv[1] = ba.y; bv[2] = ba.z; bv[3] = ba.w;
        bv[4] = bb.x; bv[5] = bb.y; bv[6] = bb.z; bv[7] = bb.w;
#pragma unroll
        for (int rr = 0; rr < 2; ++rr) {
            int row = rg + 32 * rr;
            float4 xr = {0.f, 0.f, 0.f, 0.f};
            if (base + row < N_NODES) xr = *(const float4*)&x[(size_t)(base + row) * 4];
            f16x8 hv;
#pragma unroll
            for (int j = 0; j < 8; ++j) {
                float v = bv[j] + xr.x * wv[0][j] + xr.y * wv[1][j] + xr.z * wv[2][j] + xr.w * wv[3][j];
                hv[j] = (_Float16)v;
            }
            *(f16x8*)(tile + swz(row, c8 * 2)) = hv;
        }
    }
    __syncthreads();

    const int w = tid >> 6, l = tid & 63, l16 = l & 15, lg = l >> 4;
    f32x4 acc2[2][4];
#pragma unroll
    for (int ci = 0; ci < 2; ++ci)
#pragma unroll
        for (int rt = 0; rt < 4; ++rt) acc2[ci][rt] = (f32x4){0.f, 0.f, 0.f, 0.f};
    const f16x8* W1v = (const f16x8*)W1c;
#pragma unroll
    for (int kb = 0; kb < 4; ++kb) {
        f16x8 b0  = W1v[(kb * 16 + 2 * w) * 64 + l];
        f16x8 b1f = W1v[(kb * 16 + 2 * w + 1) * 64 + l];
#pragma unroll
        for (int rt = 0; rt < 4; ++rt) {
            f16x8 a = *(const f16x8*)(tile + swz(rt * 16 + l16, kb * 64 + lg * 16));
            acc2[0][rt] = __builtin_amdgcn_mfma_f32_16x16x32_f16(a, b0,  acc2[0][rt], 0, 0, 0);
            acc2[1][rt] = __builtin_amdgcn_mfma_f32_16x16x32_f16(a, b1f, acc2[1][rt], 0, 0, 0);
        }
    }
#pragma unroll
    for (int ci = 0; ci < 2; ++ci) {
        int col = (2 * w + ci) * 16 + l16;
        float bb = (col < 128) ? b1n[col] : 0.f;
#pragma unroll
        for (int rt = 0; rt < 4; ++rt)
#pragma unroll
            for (int r = 0; r < 4; ++r) {
                int row = rt * 16 + lg * 4 + r;
                if (base + row < N_NODES)
                    PQ[(size_t)(base + row) * 256 + col] = (_Float16)(acc2[ci][rt][r] + bb);
            }
    }
}

extern "C" void kernel_launch(void* const* d_in, const int* in_sizes, int n_in,
                              void* d_out, int out_size, void* d_ws, size_t ws_size,
                              hipStream_t stream) {
    const float* x     = (const float*)d_in[0];
    const int*   ei    = (const int*)d_in[1];
    const float* ea    = (const float*)d_in[2];
    const float* W_enc = (const float*)d_in[3];
    const float* b_enc = (const float*)d_in[4];
    const float* W1    = (const float*)d_in[5];
    const float* b1    = (const float*)d_in[6];
    const float* W2    = (const float*)d_in[7];
    const float* b2    = (const float*)d_in[8];
    const float* Wg    = (const float*)d_in[9];
    const float* bg    = (const float*)d_in[10];
    const float* Wp    = (const float*)d_in[11];
    const float* bp    = (const float*)d_in[12];
    const float* Wr    = (const float*)d_in[13];
    const float* br    = (const float*)d_in[14];

    float* out = (float*)d_out;

    // ws layout (~48 MB)
    char* ws = (char*)d_ws;
    _Float16*     PQ     = (_Float16*)ws;     ws += (size_t)N_NODES * 256 * 2;   // 25.6 MB
    _Float16*     aggH   = (_Float16*)ws;     ws += (size_t)N_NODES * 128 * 2;   // 12.8 MB
    float*        agg32c = (float*)ws;        ws += (size_t)EBLK * 128 * 4;      // 2.56 MB
    uint2*        sdPE   = (uint2*)ws;        ws += (size_t)N_EDGES * 8;         // 5.12 MB
    int*          counts = (int*)ws;          ws += 200192;
    int*          cursor = (int*)ws;          ws += 200192;
    int*          bslot  = (int*)ws;          ws += 200192;
    _Float16*     W1c    = (_Float16*)ws;     ws += (size_t)131072 * 2;
    _Float16*     W2p    = (_Float16*)ws;     ws += (size_t)65536 * 2;
    int*          chunkSum  = (int*)ws;       ws += 1024;
    int*          chunkBase = (int*)ws;       ws += 1024;

    hipMemsetAsync(counts, 0, (size_t)N_NODES * 4, stream);
    hipMemsetAsync(agg32c, 0, (size_t)EBLK * 128 * 4, stream);

    count_kernel<<<N_EDGES / 256, 256, 0, stream>>>(ei, counts);
    csr_local_kernel<<<NCHUNK, 256, 0, stream>>>(counts, cursor, chunkSum, bslot, aggH);
    chunk_scan_kernel<<<1, 256, 0, stream>>>(chunkSum, chunkBase);
    scatter_kernel<<<N_EDGES / 256, 256, 0, stream>>>(ei, ea, chunkBase, cursor, sdPE);

    pack_w_kernel<<<196608 / 256, 256, 0, stream>>>(W1, W2, W1c, W2p);
    bnd_setup_kernel<<<(EBLK + 255) / 256, 256, 0, stream>>>(sdPE, bslot);

    node_enc_kernel<<<NBLK64, 512, 0, stream>>>(x, W_enc, b_enc, W1c, b1, PQ);

    for (int l = 0; l < N_LAYERS; ++l) {
        edge_gather_kernel<<<EBLK, 512, 0, stream>>>(
            PQ, sdPE,
            W1 + (size_t)l * 257 * 128 + 256 * 128,
            aggH, agg32c);
        int nl = (l < 3) ? (l + 1) : 0;
        node_layer_kernel<<<NBLK64, 512, 0, stream>>>(
            aggH, counts, bslot, agg32c,
            W2p + (size_t)l * 16384, b2 + l * HIDDEN,
            W1c + (size_t)nl * 32768, b1 + nl * HIDDEN,
            PQ, out, Wg, bg, Wp, bp, Wr, br,
            (l == N_LAYERS - 1) ? 1 : 0);
    }
}

// Round 9
// 312.929 us; speedup vs baseline: 1.0300x; 1.0300x over previous
//
#include <hip/hip_runtime.h>
#include <hip/hip_fp16.h>

#define N_NODES 50000
#define N_EDGES 640000
#define HIDDEN  128
#define N_LAYERS 4
#define TILE_E  128
#define EBLK    (N_EDGES / TILE_E)   // 5000
#define NCHUNK  196                  // ceil(50000/256)
#define NBLK64  ((N_NODES + 63) / 64)  // 782

#define OUT_GHOST  (N_NODES * HIDDEN)
#define OUT_PERIOD (OUT_GHOST + N_NODES)
#define OUT_GRAD   (OUT_PERIOD + N_NODES)

typedef _Float16 f16x8 __attribute__((ext_vector_type(8)));
typedef _Float16 f16x2 __attribute__((ext_vector_type(2)));
typedef float    f32x4 __attribute__((ext_vector_type(4)));

// LDS tile: rows x 256 bytes, XOR-swizzled (T2): byte ^= ((row&7)<<4).
__device__ __forceinline__ int swz(int row, int colbyte) {
    return (row * 256 + colbyte) ^ ((row & 7) << 4);
}

// ---- edge_index dtype self-detection (int64 LE with ids<2^31 -> odd words 0) ----
__device__ __forceinline__ int ei_is64(const int* __restrict__ ei) {
    return (ei[1] == 0 && ei[3] == 0 && ei[5] == 0) ? 1 : 0;
}
__device__ __forceinline__ int ei_src(const int* __restrict__ ei, int is64, int e) {
    return is64 ? ei[2 * e] : ei[e];
}
__device__ __forceinline__ int ei_dst(const int* __restrict__ ei, int is64, int e) {
    return is64 ? ei[2 * (N_EDGES + e)] : ei[N_EDGES + e];
}

// ---------------- CSR build ----------------
__global__ void count_kernel(const int* __restrict__ ei, int* __restrict__ counts) {
    int e = blockIdx.x * 256 + threadIdx.x;
    atomicAdd(&counts[ei_dst(ei, ei_is64(ei), e)], 1);
}

// per-chunk local exclusive scan of counts -> cursor, chunk totals -> chunkSum;
// also per-call node init (bslot=-1, zero deg-0 aggH rows).
__global__ void csr_local_kernel(const int* __restrict__ counts, int* __restrict__ cursor,
                                 int* __restrict__ chunkSum, int* __restrict__ bslot,
                                 _Float16* __restrict__ aggH) {
    __shared__ int buf[256];
    int t = threadIdx.x, i = blockIdx.x * 256 + t;
    int v = (i < N_NODES) ? counts[i] : 0;
    buf[t] = v;
    __syncthreads();
    for (int off = 1; off < 256; off <<= 1) {
        int add = (t >= off) ? buf[t - off] : 0;
        __syncthreads();
        buf[t] += add;
        __syncthreads();
    }
    if (i < N_NODES) {
        cursor[i] = buf[t] - v;   // chunk-local exclusive prefix
        bslot[i] = -1;
        if (v == 0) {
            float4 z = {0.f, 0.f, 0.f, 0.f};
#pragma unroll
            for (int k = 0; k < 16; ++k)
                *(float4*)&aggH[(size_t)i * 128 + k * 8] = z;
        }
    }
    if (t == 255) chunkSum[blockIdx.x] = buf[255];
}

__global__ void chunk_scan_kernel(const int* __restrict__ chunkSum, int* __restrict__ chunkBase) {
    __shared__ int buf[256];
    int t = threadIdx.x;
    int v = (t < NCHUNK) ? chunkSum[t] : 0;
    buf[t] = v;
    __syncthreads();
    for (int off = 1; off < 256; off <<= 1) {
        int add = (t >= off) ? buf[t - off] : 0;
        __syncthreads();
        buf[t] += add;
        __syncthreads();
    }
    if (t < NCHUNK) chunkBase[t] = buf[t] - v;
}

// rank-scatter into ONE packed 8B stream: {src16|dst16, ea_f32}
__global__ void scatter_kernel(const int* __restrict__ ei, const float* __restrict__ ea,
                               const int* __restrict__ chunkBase, int* __restrict__ cursor,
                               uint2* __restrict__ sdPE) {
    int e = blockIdx.x * 256 + threadIdx.x;
    int is64 = ei_is64(ei);
    int s = ei_src(ei, is64, e);
    int d = ei_dst(ei, is64, e);
    int p = chunkBase[d >> 8] + atomicAdd(&cursor[d], 1);
    uint2 v;
    v.x = (unsigned)s | ((unsigned)d << 16);   // N_NODES < 65536
    v.y = __float_as_uint(ea[e]);
    sdPE[p] = v;
}

// ---------------- weight pre-pack into MFMA fragment order (f16) ----------------
__global__ void pack_w_kernel(const float* __restrict__ W1, const float* __restrict__ W2,
                              _Float16* __restrict__ W1c, _Float16* __restrict__ W2p) {
    int id = blockIdx.x * 256 + threadIdx.x;
    if (id < 131072) {
        int j = id & 7, l = (id >> 3) & 63, c = (id >> 9) & 15, kb = (id >> 13) & 3, lay = id >> 15;
        int k = kb * 32 + (l >> 4) * 8 + j, col = c * 16 + (l & 15);
        const float* Wl = W1 + (size_t)lay * 257 * 128;
        W1c[id] = (_Float16)((col < 128) ? Wl[(size_t)k * 128 + col]
                                         : Wl[(size_t)(128 + k) * 128 + (col - 128)]);
    } else if (id < 196608) {
        int id2 = id - 131072;
        int j = id2 & 7, l = (id2 >> 3) & 63, c = (id2 >> 9) & 7, kb = (id2 >> 12) & 3, lay = id2 >> 14;
        int k = kb * 32 + (l >> 4) * 8 + j, col = c * 16 + (l & 15);
        W2p[id2] = (_Float16)W2[(size_t)lay * 128 * 128 + (size_t)k * 128 + col];
    }
}

// ---------------- boundary slots (valid while max degree < TILE_E) ----------------
__global__ void bnd_setup_kernel(const uint2* __restrict__ sdPE, int* __restrict__ bslot) {
    int t = blockIdx.x * 256 + threadIdx.x;
    if (t >= 1 && t < EBLK) {
        unsigned dp = sdPE[t * TILE_E - 1].x >> 16;
        unsigned d0 = sdPE[t * TILE_E].x >> 16;
        if (dp == d0) bslot[d0] = t;
    }
}

// ---------------- edge kernel: gather P'[dst]+Q[src] -> hidden -> segment-sum ----------------
// P' has b1 pre-folded; hidden = relu(P' + Q + ea*w1last).
// Round-7 proven structure: LDS-staged indices; pv/qv load+consume adjacent
// (compiler pipelines within ~32 VGPRs at 8 blocks/CU).
__global__ __launch_bounds__(512, 8)
void edge_gather_kernel(const _Float16* __restrict__ PQ,
                        const uint2* __restrict__ sdPE,
                        const float* __restrict__ w1last,
                        _Float16* __restrict__ aggH, float* __restrict__ agg32c) {
    __shared__ __align__(16) unsigned char tile[TILE_E * 256];
    __shared__ int dstL[TILE_E];
    __shared__ int srcL[TILE_E];
    __shared__ _Float16 eaL[TILE_E];
    __shared__ int segStart[TILE_E + 1];
    __shared__ int nsegS, contP, contN;

    const int tid = threadIdx.x;
    const int bid = (blockIdx.x & 7) * (EBLK / 8) + (blockIdx.x >> 3);  // XCD swizzle
    const int e_base = bid * TILE_E;

    // P0: coalesced packed-index load -> LDS
    if (tid < TILE_E) {
        uint2 u = sdPE[e_base + tid];
        srcL[tid] = (int)(u.x & 0xFFFFu);
        dstL[tid] = (int)(u.x >> 16);
        eaL[tid]  = (_Float16)__uint_as_float(u.y);
    } else if (tid == TILE_E) {
        contP = (e_base > 0 && (sdPE[e_base - 1].x >> 16) == (sdPE[e_base].x >> 16)) ? 1 : 0;
    } else if (tid == TILE_E + 1) {
        contN = (e_base + TILE_E < N_EDGES &&
                 (sdPE[e_base + TILE_E - 1].x >> 16) == (sdPE[e_base + TILE_E].x >> 16)) ? 1 : 0;
    }
    __syncthreads();

    // segment ranks (waves 0,1)
    if (tid < 128) {
        int lane = tid & 63;
        int fl_lo = (lane == 0) ? 1 : (dstL[lane] != dstL[lane - 1]);
        unsigned long long m0 = __ballot(fl_lo);
        if (tid < 64) {
            if (fl_lo) segStart[__popcll(m0 & ((1ull << lane) - 1))] = lane;
        } else {
            int j = 64 + lane;
            int fl = (dstL[j] != dstL[j - 1]);
            unsigned long long m1 = __ballot(fl);
            int nlo = __popcll(m0);
            if (fl) segStart[nlo + __popcll(m1 & ((1ull << lane) - 1))] = j;
            if (lane == 0) {
                int ns = nlo + __popcll(m1);
                nsegS = ns;
                segStart[ns] = TILE_E;
            }
        }
    }

    // P1: preload gathers, packed-f16 hidden = relu(P' + Q + ea*wl)
    {
        const int t16 = tid & 15, rg = tid >> 4;
        const int c8 = t16 * 8;

        f16x8 pv[4], qv[4];
#pragma unroll
        for (int rr = 0; rr < 4; ++rr) {
            int row = rg + 32 * rr;
            pv[rr] = *(const f16x8*)&PQ[(size_t)dstL[row] * 256 + c8];
            qv[rr] = *(const f16x8*)&PQ[(size_t)srcL[row] * 256 + 128 + c8];
        }

        f16x8 wl8, z8;
#pragma unroll
        for (int j = 0; j < 8; ++j) {
            wl8[j] = (_Float16)w1last[c8 + j];
            z8[j]  = (_Float16)0.f;
        }

#pragma unroll
        for (int rr = 0; rr < 4; ++rr) {
            int row = rg + 32 * rr;
            f16x8 t = pv[rr] + qv[rr] + wl8 * eaL[row];
            f16x8 hv = __builtin_elementwise_max(t, z8);
            *(f16x8*)(tile + swz(row, c8 * 2)) = hv;
        }
    }
    __syncthreads();

    // P2: per-segment column sums; interior -> f16 store, boundary -> slot atomics
    {
        int col2 = (tid & 63) * 2, sh = tid >> 6;
        int ns = nsegS, cP = contP, cN = contN;
        for (int s = sh; s < ns; s += 8) {
            int b = segStart[s], en = segStart[s + 1];
            float s0 = 0.f, s1 = 0.f;
            for (int e2 = b; e2 < en; ++e2) {
                f16x2 hv = *(const f16x2*)(tile + swz(e2, col2 * 2));
                s0 += (float)hv[0];
                s1 += (float)hv[1];
            }
            bool isP = (s == 0 && cP), isN = (s == ns - 1 && cN);
            if (isP || isN) {
                int slot = isP ? bid : bid + 1;
                atomicAdd(&agg32c[(size_t)slot * 128 + col2], s0);
                atomicAdd(&agg32c[(size_t)slot * 128 + col2 + 1], s1);
            } else {
                int node = dstL[b];
                f16x2 o; o[0] = (_Float16)s0; o[1] = (_Float16)s1;
                *(f16x2*)&aggH[(size_t)node * 128 + col2] = o;
            }
        }
    }
}

// ---------------- node kernel (64 rows/block, 8 waves) ----------------
__global__ __launch_bounds__(512, 6)
void node_layer_kernel(const _Float16* __restrict__ aggH,
                       const int* __restrict__ counts,
                       const int* __restrict__ bslot, float* __restrict__ agg32c,
                       const _Float16* __restrict__ W2p, const float* __restrict__ b2,
                       const _Float16* __restrict__ W1c, const float* __restrict__ b1n,
                       _Float16* __restrict__ PQ, float* __restrict__ out,
                       const float* __restrict__ Wg, const float* __restrict__ bg,
                       const float* __restrict__ Wp, const float* __restrict__ bp,
                       const float* __restrict__ Wr, const float* __restrict__ br,
                       int last) {
    __shared__ __align__(16) unsigned char tile[64 * 256];
    __shared__ int degL[64];
    __shared__ float hw[512];

    const int tid = threadIdx.x;
    const int base = blockIdx.x * 64;

    {
        const int t16 = tid & 15, rg = tid >> 4;
#pragma unroll
        for (int rr = 0; rr < 2; ++rr) {
            int row = rg + 32 * rr;
            int n = base + row;
            f16x8 v = {0, 0, 0, 0, 0, 0, 0, 0};
            if (n < N_NODES) {
                int bs = bslot[n];
                if (bs >= 0) {
                    float* ap = &agg32c[(size_t)bs * 128 + t16 * 8];
                    float4 a = *(const float4*)ap;
                    float4 b = *(const float4*)(ap + 4);
                    v[0] = (_Float16)a.x; v[1] = (_Float16)a.y;
                    v[2] = (_Float16)a.z; v[3] = (_Float16)a.w;
                    v[4] = (_Float16)b.x; v[5] = (_Float16)b.y;
                    v[6] = (_Float16)b.z; v[7] = (_Float16)b.w;
                    float4 z = {0.f, 0.f, 0.f, 0.f};   // re-zero for next layer
                    *(float4*)ap = z; *(float4*)(ap + 4) = z;
                } else {
                    v = *(const f16x8*)&aggH[(size_t)n * 128 + t16 * 8];
                }
            }
            *(f16x8*)(tile + swz(row, t16 * 16)) = v;
        }
        if (tid < 64) degL[tid] = (base + tid < N_NODES) ? counts[base + tid] : 0;
        if (last) {
            if (tid < 128)       hw[tid] = Wg[tid];
            else if (tid < 256)  hw[tid] = Wp[tid - 128];
            else                 hw[tid] = Wr[tid - 256];
        }
    }
    __syncthreads();

    const int w = tid >> 6, l = tid & 63, l16 = l & 15, lg = l >> 4;

    // GEMM_h: wave w -> h cols [16w, 16w+16)
    f32x4 acc[4];
#pragma unroll
    for (int rt = 0; rt < 4; ++rt) acc[rt] = (f32x4){0.f, 0.f, 0.f, 0.f};
    const f16x8* W2v = (const f16x8*)W2p;
#pragma unroll
    for (int kb = 0; kb < 4; ++kb) {
        f16x8 bf = W2v[(kb * 8 + w) * 64 + l];
#pragma unroll
        for (int rt = 0; rt < 4; ++rt) {
            f16x8 a = *(const f16x8*)(tile + swz(rt * 16 + l16, kb * 64 + lg * 16));
            acc[rt] = __builtin_amdgcn_mfma_f32_16x16x32_f16(a, bf, acc[rt], 0, 0, 0);
        }
    }
    __syncthreads();   // all A-reads done before h overwrites tile

    {
        int col = 16 * w + l16;
        float bias = b2[col];
#pragma unroll
        for (int rt = 0; rt < 4; ++rt)
#pragma unroll
            for (int r = 0; r < 4; ++r) {
                int row = rt * 16 + lg * 4 + r;
                float h = fmaxf(acc[rt][r] + (float)degL[row] * bias, 0.f);
                *(_Float16*)(tile + swz(row, col * 2)) = (_Float16)h;
                if (last && base + row < N_NODES)
                    out[(size_t)(base + row) * 128 + col] = h;
            }
    }
    __syncthreads();

    if (last) {
        // fused heads: 8 threads/node, 16 cols each, 3-level shuffle reduce
        int r = tid >> 3, part = tid & 7;
        float sg = 0.f, sp = 0.f, s0 = 0.f, s1 = 0.f;
#pragma unroll
        for (int i = 0; i < 8; ++i) {
            int c = part * 16 + i * 2;
            f16x2 hv = *(const f16x2*)(tile + swz(r, c * 2));
            float h0 = (float)hv[0], h1 = (float)hv[1];
            sg += h0 * hw[c] + h1 * hw[c + 1];
            sp += h0 * hw[128 + c] + h1 * hw[128 + c + 1];
            s0 += h0 * hw[256 + c * 2] + h1 * hw[256 + (c + 1) * 2];
            s1 += h0 * hw[256 + c * 2 + 1] + h1 * hw[256 + (c + 1) * 2 + 1];
        }
        sg += __shfl_xor(sg, 1); sg += __shfl_xor(sg, 2); sg += __shfl_xor(sg, 4);
        sp += __shfl_xor(sp, 1); sp += __shfl_xor(sp, 2); sp += __shfl_xor(sp, 4);
        s0 += __shfl_xor(s0, 1); s0 += __shfl_xor(s0, 2); s0 += __shfl_xor(s0, 4);
        s1 += __shfl_xor(s1, 1); s1 += __shfl_xor(s1, 2); s1 += __shfl_xor(s1, 4);
        int n = base + r;
        if (part == 0 && n < N_NODES) {
            float g = sg + bg[0];
            out[OUT_GHOST + n]        = 1.f / (1.f + expf(-g));
            out[OUT_PERIOD + n]       = sp + bp[0];
            out[OUT_GRAD + n * 2]     = s0 + br[0];
            out[OUT_GRAD + n * 2 + 1] = s1 + br[1];
        }
        return;
    }

    // GEMM_PQ: wave w -> cols [32w, 32w+32) of 256; fold next-layer b1 into P side
    f32x4 acc2[2][4];
#pragma unroll
    for (int ci = 0; ci < 2; ++ci)
#pragma unroll
        for (int rt = 0; rt < 4; ++rt) acc2[ci][rt] = (f32x4){0.f, 0.f, 0.f, 0.f};
    const f16x8* W1v = (const f16x8*)W1c;
#pragma unroll
    for (int kb = 0; kb < 4; ++kb) {
        f16x8 b0  = W1v[(kb * 16 + 2 * w) * 64 + l];
        f16x8 b1f = W1v[(kb * 16 + 2 * w + 1) * 64 + l];
#pragma unroll
        for (int rt = 0; rt < 4; ++rt) {
            f16x8 a = *(const f16x8*)(tile + swz(rt * 16 + l16, kb * 64 + lg * 16));
            acc2[0][rt] = __builtin_amdgcn_mfma_f32_16x16x32_f16(a, b0,  acc2[0][rt], 0, 0, 0);
            acc2[1][rt] = __builtin_amdgcn_mfma_f32_16x16x32_f16(a, b1f, acc2[1][rt], 0, 0, 0);
        }
    }
#pragma unroll
    for (int ci = 0; ci < 2; ++ci) {
        int col = (2 * w + ci) * 16 + l16;
        float bb = (col < 128) ? b1n[col] : 0.f;
#pragma unroll
        for (int rt = 0; rt < 4; ++rt)
#pragma unroll
            for (int r = 0; r < 4; ++r) {
                int row = rt * 16 + lg * 4 + r;
                if (base + row < N_NODES)
                    PQ[(size_t)(base + row) * 256 + col] = (_Float16)(acc2[ci][rt][r] + bb);
            }
    }
}

// ---------------- encoder (64 rows/block) ----------------
__global__ __launch_bounds__(512, 6)
void node_enc_kernel(const float* __restrict__ x,
                     const float* __restrict__ Wenc, const float* __restrict__ benc,
                     const _Float16* __restrict__ W1c, const float* __restrict__ b1n,
                     _Float16* __restrict__ PQ) {
    __shared__ __align__(16) unsigned char tile[64 * 256];
    const int tid = threadIdx.x;
    const int base = blockIdx.x * 64;

    {
        const int t16 = tid & 15, rg = tid >> 4;
        const int c8 = t16 * 8;
        float wv[4][8], bv[8];
#pragma unroll
        for (int i = 0; i < 4; ++i) {
            float4 a = *(const float4*)&Wenc[i * 128 + c8];
            float4 b = *(const float4*)&Wenc[i * 128 + c8 + 4];
            wv[i][0] = a.x; wv[i][1] = a.y; wv[i][2] = a.z; wv[i][3] = a.w;
            wv[i][4] = b.x; wv[i][5] = b.y; wv[i][6] = b.z; wv[i][7] = b.w;
        }
        float4 ba = *(const float4*)&benc[c8];
        float4 bb = *(const float4*)&benc[c8 + 4];
        bv[0] = ba.x; bv[1] = ba.y; bv[2] = ba.z; bv[3] = ba.w;
        bv[4] = bb.x; bv[5] = bb.y; bv[6] = bb.z; bv[7] = bb.w;
#pragma unroll
        for (int rr = 0; rr < 2; ++rr) {
            int row = rg + 32 * rr;
            float4 xr = {0.f, 0.f, 0.f, 0.f};
            if (base + row < N_NODES) xr = *(const float4*)&x[(size_t)(base + row) * 4];
            f16x8 hv;
#pragma unroll
            for (int j = 0; j < 8; ++j) {
                float v = bv[j] + xr.x * wv[0][j] + xr.y * wv[1][j] + xr.z * wv[2][j] + xr.w * wv[3][j];
                hv[j] = (_Float16)v;
            }
            *(f16x8*)(tile + swz(row, c8 * 2)) = hv;
        }
    }
    __syncthreads();

    const int w = tid >> 6, l = tid & 63, l16 = l & 15, lg = l >> 4;
    f32x4 acc2[2][4];
#pragma unroll
    for (int ci = 0; ci < 2; ++ci)
#pragma unroll
        for (int rt = 0; rt < 4; ++rt) acc2[ci][rt] = (f32x4){0.f, 0.f, 0.f, 0.f};
    const f16x8* W1v = (const f16x8*)W1c;
#pragma unroll
    for (int kb = 0; kb < 4; ++kb) {
        f16x8 b0  = W1v[(kb * 16 + 2 * w) * 64 + l];
        f16x8 b1f = W1v[(kb * 16 + 2 * w + 1) * 64 + l];
#pragma unroll
        for (int rt = 0; rt < 4; ++rt) {
            f16x8 a = *(const f16x8*)(tile + swz(rt * 16 + l16, kb * 64 + lg * 16));
            acc2[0][rt] = __builtin_amdgcn_mfma_f32_16x16x32_f16(a, b0,  acc2[0][rt], 0, 0, 0);
            acc2[1][rt] = __builtin_amdgcn_mfma_f32_16x16x32_f16(a, b1f, acc2[1][rt], 0, 0, 0);
        }
    }
#pragma unroll
    for (int ci = 0; ci < 2; ++ci) {
        int col = (2 * w + ci) * 16 + l16;
        float bb = (col < 128) ? b1n[col] : 0.f;
#pragma unroll
        for (int rt = 0; rt < 4; ++rt)
#pragma unroll
            for (int r = 0; r < 4; ++r) {
                int row = rt * 16 + lg * 4 + r;
                if (base + row < N_NODES)
                    PQ[(size_t)(base + row) * 256 + col] = (_Float16)(acc2[ci][rt][r] + bb);
            }
    }
}

extern "C" void kernel_launch(void* const* d_in, const int* in_sizes, int n_in,
                              void* d_out, int out_size, void* d_ws, size_t ws_size,
                              hipStream_t stream) {
    const float* x     = (const float*)d_in[0];
    const int*   ei    = (const int*)d_in[1];
    const float* ea    = (const float*)d_in[2];
    const float* W_enc = (const float*)d_in[3];
    const float* b_enc = (const float*)d_in[4];
    const float* W1    = (const float*)d_in[5];
    const float* b1    = (const float*)d_in[6];
    const float* W2    = (const float*)d_in[7];
    const float* b2    = (const float*)d_in[8];
    const float* Wg    = (const float*)d_in[9];
    const float* bg    = (const float*)d_in[10];
    const float* Wp    = (const float*)d_in[11];
    const float* bp    = (const float*)d_in[12];
    const float* Wr    = (const float*)d_in[13];
    const float* br    = (const float*)d_in[14];

    float* out = (float*)d_out;

    // ws layout (~48 MB)
    char* ws = (char*)d_ws;
    _Float16*     PQ     = (_Float16*)ws;     ws += (size_t)N_NODES * 256 * 2;   // 25.6 MB
    _Float16*     aggH   = (_Float16*)ws;     ws += (size_t)N_NODES * 128 * 2;   // 12.8 MB
    float*        agg32c = (float*)ws;        ws += (size_t)EBLK * 128 * 4;      // 2.56 MB
    uint2*        sdPE   = (uint2*)ws;        ws += (size_t)N_EDGES * 8;         // 5.12 MB
    int*          counts = (int*)ws;          ws += 200192;
    int*          cursor = (int*)ws;          ws += 200192;
    int*          bslot  = (int*)ws;          ws += 200192;
    _Float16*     W1c    = (_Float16*)ws;     ws += (size_t)131072 * 2;
    _Float16*     W2p    = (_Float16*)ws;     ws += (size_t)65536 * 2;
    int*          chunkSum  = (int*)ws;       ws += 1024;
    int*          chunkBase = (int*)ws;       ws += 1024;

    hipMemsetAsync(counts, 0, (size_t)N_NODES * 4, stream);
    hipMemsetAsync(agg32c, 0, (size_t)EBLK * 128 * 4, stream);

    count_kernel<<<N_EDGES / 256, 256, 0, stream>>>(ei, counts);
    csr_local_kernel<<<NCHUNK, 256, 0, stream>>>(counts, cursor, chunkSum, bslot, aggH);
    chunk_scan_kernel<<<1, 256, 0, stream>>>(chunkSum, chunkBase);
    scatter_kernel<<<N_EDGES / 256, 256, 0, stream>>>(ei, ea, chunkBase, cursor, sdPE);

    pack_w_kernel<<<196608 / 256, 256, 0, stream>>>(W1, W2, W1c, W2p);
    bnd_setup_kernel<<<(EBLK + 255) / 256, 256, 0, stream>>>(sdPE, bslot);

    node_enc_kernel<<<NBLK64, 512, 0, stream>>>(x, W_enc, b_enc, W1c, b1, PQ);

    for (int l = 0; l < N_LAYERS; ++l) {
        edge_gather_kernel<<<EBLK, 512, 0, stream>>>(
            PQ, sdPE,
            W1 + (size_t)l * 257 * 128 + 256 * 128,
            aggH, agg32c);
        int nl = (l < 3) ? (l + 1) : 0;
        node_layer_kernel<<<NBLK64, 512, 0, stream>>>(
            aggH, counts, bslot, agg32c,
            W2p + (size_t)l * 16384, b2 + l * HIDDEN,
            W1c + (size_t)nl * 32768, b1 + nl * HIDDEN,
            PQ, out, Wg, bg, Wp, bp, Wr, br,
            (l == N_LAYERS - 1) ? 1 : 0);
    }
}

// Round 10
// 309.884 us; speedup vs baseline: 1.0401x; 1.0098x over previous
//
#include <hip/hip_runtime.h>
#include <hip/hip_fp16.h>

#define N_NODES 50000
#define N_EDGES 640000
#define HIDDEN  128
#define N_LAYERS 4
#define TILE_E  128
#define EBLK    (N_EDGES / TILE_E)   // 5000
#define NCHUNK  196                  // ceil(50000/256)
#define NBLK64  ((N_NODES + 63) / 64)  // 782
#define NC      50048                // padded per-class stride (ints)
#define PSLICE  (N_EDGES / 8)        // 80000

#define OUT_GHOST  (N_NODES * HIDDEN)
#define OUT_PERIOD (OUT_GHOST + N_NODES)
#define OUT_GRAD   (OUT_PERIOD + N_NODES)

typedef _Float16 f16x8 __attribute__((ext_vector_type(8)));
typedef _Float16 f16x2 __attribute__((ext_vector_type(2)));
typedef float    f32x4 __attribute__((ext_vector_type(4)));

// LDS tile: rows x 256 bytes, XOR-swizzled (T2): byte ^= ((row&7)<<4).
__device__ __forceinline__ int swz(int row, int colbyte) {
    return (row * 256 + colbyte) ^ ((row & 7) << 4);
}

// ---- edge_index dtype self-detection (int64 LE with ids<2^31 -> odd words 0) ----
__device__ __forceinline__ int ei_is64(const int* __restrict__ ei) {
    return (ei[1] == 0 && ei[3] == 0 && ei[5] == 0) ? 1 : 0;
}
__device__ __forceinline__ int ei_src(const int* __restrict__ ei, int is64, int e) {
    return is64 ? ei[2 * e] : ei[e];
}
__device__ __forceinline__ int ei_dst(const int* __restrict__ ei, int is64, int e) {
    return is64 ? ei[2 * (N_EDGES + e)] : ei[N_EDGES + e];
}

// ---------------- CSR build: class-privatized histogram ----------------
__global__ void count_kernel(const int* __restrict__ ei, int* __restrict__ counts8) {
    int e = blockIdx.x * 256 + threadIdx.x;
    int cls = blockIdx.x & 7;
    atomicAdd(&counts8[cls * NC + ei_dst(ei, ei_is64(ei), e)], 1);
}

// per-chunk local scan of per-node totals -> per-class cursors with class prefix;
// deg, chunk totals, bslot=-1, zero deg-0 aggH rows.
__global__ void csr_local_kernel(const int* __restrict__ counts8,
                                 int* __restrict__ deg,
                                 int* __restrict__ cursorClass,
                                 int* __restrict__ chunkSum,
                                 int* __restrict__ bslot,
                                 _Float16* __restrict__ aggH) {
    __shared__ int buf[256];
    int t = threadIdx.x, i = blockIdx.x * 256 + t;
    int c8[8]; int v = 0;
#pragma unroll
    for (int c = 0; c < 8; ++c) {
        c8[c] = (i < N_NODES) ? counts8[c * NC + i] : 0;
        v += c8[c];
    }
    buf[t] = v;
    __syncthreads();
    for (int off = 1; off < 256; off <<= 1) {
        int add = (t >= off) ? buf[t - off] : 0;
        __syncthreads();
        buf[t] += add;
        __syncthreads();
    }
    if (i < N_NODES) {
        int run = buf[t] - v;   // chunk-local exclusive prefix
#pragma unroll
        for (int c = 0; c < 8; ++c) { cursorClass[c * NC + i] = run; run += c8[c]; }
        deg[i] = v;
        bslot[i] = -1;
        if (v == 0) {
            float4 z = {0.f, 0.f, 0.f, 0.f};
#pragma unroll
            for (int k = 0; k < 16; ++k)
                *(float4*)&aggH[(size_t)i * 128 + k * 8] = z;
        }
    }
    if (t == 255) chunkSum[blockIdx.x] = buf[255];
}

__global__ void chunk_scan_kernel(const int* __restrict__ chunkSum, int* __restrict__ chunkBase) {
    __shared__ int buf[256];
    int t = threadIdx.x;
    int v = (t < NCHUNK) ? chunkSum[t] : 0;
    buf[t] = v;
    __syncthreads();
    for (int off = 1; off < 256; off <<= 1) {
        int add = (t >= off) ? buf[t - off] : 0;
        __syncthreads();
        buf[t] += add;
        __syncthreads();
    }
    if (t < NCHUNK) chunkBase[t] = buf[t] - v;
}

// phase A: rank each edge (class-private atomics), write p + packed payload COALESCED
__global__ void rankA_kernel(const int* __restrict__ ei, const float* __restrict__ ea,
                             const int* __restrict__ chunkBase, int* __restrict__ cursorClass,
                             int* __restrict__ pArr, uint2* __restrict__ packedArr) {
    int e = blockIdx.x * 256 + threadIdx.x;
    int cls = blockIdx.x & 7;
    int is64 = ei_is64(ei);
    int s = ei_src(ei, is64, e);
    int d = ei_dst(ei, is64, e);
    int p = chunkBase[d >> 8] + atomicAdd(&cursorClass[cls * NC + d], 1);
    pArr[e] = p;
    uint2 v;
    v.x = (unsigned)s | ((unsigned)d << 16);   // N_NODES < 65536
    v.y = __float_as_uint(ea[e]);
    packedArr[e] = v;
}

// phase B: 8 p-range replicas permute payload into sorted stream (XCD-local lines)
__global__ void rankB_kernel(const int* __restrict__ pArr, const uint2* __restrict__ packedArr,
                             uint2* __restrict__ sdPE) {
    int r = blockIdx.x & 7;
    int e = (blockIdx.x >> 3) * 256 + threadIdx.x;
    int p = pArr[e];
    if ((unsigned)p / PSLICE == (unsigned)r) sdPE[p] = packedArr[e];
}

// ---------------- weight pre-pack into MFMA fragment order (f16) ----------------
__global__ void pack_w_kernel(const float* __restrict__ W1, const float* __restrict__ W2,
                              _Float16* __restrict__ W1c, _Float16* __restrict__ W2p) {
    int id = blockIdx.x * 256 + threadIdx.x;
    if (id < 131072) {
        int j = id & 7, l = (id >> 3) & 63, c = (id >> 9) & 15, kb = (id >> 13) & 3, lay = id >> 15;
        int k = kb * 32 + (l >> 4) * 8 + j, col = c * 16 + (l & 15);
        const float* Wl = W1 + (size_t)lay * 257 * 128;
        W1c[id] = (_Float16)((col < 128) ? Wl[(size_t)k * 128 + col]
                                         : Wl[(size_t)(128 + k) * 128 + (col - 128)]);
    } else if (id < 196608) {
        int id2 = id - 131072;
        int j = id2 & 7, l = (id2 >> 3) & 63, c = (id2 >> 9) & 7, kb = (id2 >> 12) & 3, lay = id2 >> 14;
        int k = kb * 32 + (l >> 4) * 8 + j, col = c * 16 + (l & 15);
        W2p[id2] = (_Float16)W2[(size_t)lay * 128 * 128 + (size_t)k * 128 + col];
    }
}

// ---------------- boundary slots (valid while max degree < TILE_E) ----------------
__global__ void bnd_setup_kernel(const uint2* __restrict__ sdPE, int* __restrict__ bslot) {
    int t = blockIdx.x * 256 + threadIdx.x;
    if (t >= 1 && t < EBLK) {
        unsigned dp = sdPE[t * TILE_E - 1].x >> 16;
        unsigned d0 = sdPE[t * TILE_E].x >> 16;
        if (dp == d0) bslot[d0] = t;
    }
}

// ---------------- edge kernel: gather P'[dst]+Q[src] -> hidden -> segment-sum ----------------
// P' has b1 pre-folded; hidden = relu(P' + Q + ea*w1last). Round-7 proven structure.
__global__ __launch_bounds__(512, 8)
void edge_gather_kernel(const _Float16* __restrict__ PQ,
                        const uint2* __restrict__ sdPE,
                        const float* __restrict__ w1last,
                        _Float16* __restrict__ aggH, float* __restrict__ agg32c) {
    __shared__ __align__(16) unsigned char tile[TILE_E * 256];
    __shared__ int dstL[TILE_E];
    __shared__ int srcL[TILE_E];
    __shared__ _Float16 eaL[TILE_E];
    __shared__ int segStart[TILE_E + 1];
    __shared__ int nsegS, contP, contN;

    const int tid = threadIdx.x;
    const int bid = (blockIdx.x & 7) * (EBLK / 8) + (blockIdx.x >> 3);  // XCD swizzle
    const int e_base = bid * TILE_E;

    // P0: coalesced packed-index load -> LDS
    if (tid < TILE_E) {
        uint2 u = sdPE[e_base + tid];
        srcL[tid] = (int)(u.x & 0xFFFFu);
        dstL[tid] = (int)(u.x >> 16);
        eaL[tid]  = (_Float16)__uint_as_float(u.y);
    } else if (tid == TILE_E) {
        contP = (e_base > 0 && (sdPE[e_base - 1].x >> 16) == (sdPE[e_base].x >> 16)) ? 1 : 0;
    } else if (tid == TILE_E + 1) {
        contN = (e_base + TILE_E < N_EDGES &&
                 (sdPE[e_base + TILE_E - 1].x >> 16) == (sdPE[e_base + TILE_E].x >> 16)) ? 1 : 0;
    }
    __syncthreads();

    // segment ranks (waves 0,1)
    if (tid < 128) {
        int lane = tid & 63;
        int fl_lo = (lane == 0) ? 1 : (dstL[lane] != dstL[lane - 1]);
        unsigned long long m0 = __ballot(fl_lo);
        if (tid < 64) {
            if (fl_lo) segStart[__popcll(m0 & ((1ull << lane) - 1))] = lane;
        } else {
            int j = 64 + lane;
            int fl = (dstL[j] != dstL[j - 1]);
            unsigned long long m1 = __ballot(fl);
            int nlo = __popcll(m0);
            if (fl) segStart[nlo + __popcll(m1 & ((1ull << lane) - 1))] = j;
            if (lane == 0) {
                int ns = nlo + __popcll(m1);
                nsegS = ns;
                segStart[ns] = TILE_E;
            }
        }
    }

    // P1: preload gathers, packed-f16 hidden = relu(P' + Q + ea*wl)
    {
        const int t16 = tid & 15, rg = tid >> 4;
        const int c8 = t16 * 8;

        f16x8 pv[4], qv[4];
#pragma unroll
        for (int rr = 0; rr < 4; ++rr) {
            int row = rg + 32 * rr;
            pv[rr] = *(const f16x8*)&PQ[(size_t)dstL[row] * 256 + c8];
            qv[rr] = *(const f16x8*)&PQ[(size_t)srcL[row] * 256 + 128 + c8];
        }

        f16x8 wl8, z8;
#pragma unroll
        for (int j = 0; j < 8; ++j) {
            wl8[j] = (_Float16)w1last[c8 + j];
            z8[j]  = (_Float16)0.f;
        }

#pragma unroll
        for (int rr = 0; rr < 4; ++rr) {
            int row = rg + 32 * rr;
            f16x8 t = pv[rr] + qv[rr] + wl8 * eaL[row];
            f16x8 hv = __builtin_elementwise_max(t, z8);
            *(f16x8*)(tile + swz(row, c8 * 2)) = hv;
        }
    }
    __syncthreads();

    // P2: per-segment column sums; interior -> f16 store, boundary -> slot atomics
    {
        int col2 = (tid & 63) * 2, sh = tid >> 6;
        int ns = nsegS, cP = contP, cN = contN;
        for (int s = sh; s < ns; s += 8) {
            int b = segStart[s], en = segStart[s + 1];
            float s0 = 0.f, s1 = 0.f;
            for (int e2 = b; e2 < en; ++e2) {
                f16x2 hv = *(const f16x2*)(tile + swz(e2, col2 * 2));
                s0 += (float)hv[0];
                s1 += (float)hv[1];
            }
            bool isP = (s == 0 && cP), isN = (s == ns - 1 && cN);
            if (isP || isN) {
                int slot = isP ? bid : bid + 1;
                atomicAdd(&agg32c[(size_t)slot * 128 + col2], s0);
                atomicAdd(&agg32c[(size_t)slot * 128 + col2 + 1], s1);
            } else {
                int node = dstL[b];
                f16x2 o; o[0] = (_Float16)s0; o[1] = (_Float16)s1;
                *(f16x2*)&aggH[(size_t)node * 128 + col2] = o;
            }
        }
    }
}

// ---------------- node kernel (64 rows/block, 8 waves) ----------------
__global__ __launch_bounds__(512, 6)
void node_layer_kernel(const _Float16* __restrict__ aggH,
                       const int* __restrict__ deg,
                       const int* __restrict__ bslot, float* __restrict__ agg32c,
                       const _Float16* __restrict__ W2p, const float* __restrict__ b2,
                       const _Float16* __restrict__ W1c, const float* __restrict__ b1n,
                       _Float16* __restrict__ PQ, float* __restrict__ out,
                       const float* __restrict__ Wg, const float* __restrict__ bg,
                       const float* __restrict__ Wp, const float* __restrict__ bp,
                       const float* __restrict__ Wr, const float* __restrict__ br,
                       int last) {
    __shared__ __align__(16) unsigned char tile[64 * 256];
    __shared__ int degL[64];
    __shared__ float hw[512];

    const int tid = threadIdx.x;
    const int base = blockIdx.x * 64;

    {
        const int t16 = tid & 15, rg = tid >> 4;
#pragma unroll
        for (int rr = 0; rr < 2; ++rr) {
            int row = rg + 32 * rr;
            int n = base + row;
            f16x8 v = {0, 0, 0, 0, 0, 0, 0, 0};
            if (n < N_NODES) {
                int bs = bslot[n];
                if (bs >= 0) {
                    float* ap = &agg32c[(size_t)bs * 128 + t16 * 8];
                    float4 a = *(const float4*)ap;
                    float4 b = *(const float4*)(ap + 4);
                    v[0] = (_Float16)a.x; v[1] = (_Float16)a.y;
                    v[2] = (_Float16)a.z; v[3] = (_Float16)a.w;
                    v[4] = (_Float16)b.x; v[5] = (_Float16)b.y;
                    v[6] = (_Float16)b.z; v[7] = (_Float16)b.w;
                    float4 z = {0.f, 0.f, 0.f, 0.f};   // re-zero for next layer
                    *(float4*)ap = z; *(float4*)(ap + 4) = z;
                } else {
                    v = *(const f16x8*)&aggH[(size_t)n * 128 + t16 * 8];
                }
            }
            *(f16x8*)(tile + swz(row, t16 * 16)) = v;
        }
        if (tid < 64) degL[tid] = (base + tid < N_NODES) ? deg[base + tid] : 0;
        if (last) {
            if (tid < 128)       hw[tid] = Wg[tid];
            else if (tid < 256)  hw[tid] = Wp[tid - 128];
            else                 hw[tid] = Wr[tid - 256];
        }
    }
    __syncthreads();

    const int w = tid >> 6, l = tid & 63, l16 = l & 15, lg = l >> 4;

    // GEMM_h: wave w -> h cols [16w, 16w+16)
    f32x4 acc[4];
#pragma unroll
    for (int rt = 0; rt < 4; ++rt) acc[rt] = (f32x4){0.f, 0.f, 0.f, 0.f};
    const f16x8* W2v = (const f16x8*)W2p;
#pragma unroll
    for (int kb = 0; kb < 4; ++kb) {
        f16x8 bf = W2v[(kb * 8 + w) * 64 + l];
#pragma unroll
        for (int rt = 0; rt < 4; ++rt) {
            f16x8 a = *(const f16x8*)(tile + swz(rt * 16 + l16, kb * 64 + lg * 16));
            acc[rt] = __builtin_amdgcn_mfma_f32_16x16x32_f16(a, bf, acc[rt], 0, 0, 0);
        }
    }
    __syncthreads();   // all A-reads done before h overwrites tile

    {
        int col = 16 * w + l16;
        float bias = b2[col];
#pragma unroll
        for (int rt = 0; rt < 4; ++rt)
#pragma unroll
            for (int r = 0; r < 4; ++r) {
                int row = rt * 16 + lg * 4 + r;
                float h = fmaxf(acc[rt][r] + (float)degL[row] * bias, 0.f);
                *(_Float16*)(tile + swz(row, col * 2)) = (_Float16)h;
                if (last && base + row < N_NODES)
                    out[(size_t)(base + row) * 128 + col] = h;
            }
    }
    __syncthreads();

    if (last) {
        // fused heads: 8 threads/node, 16 cols each, 3-level shuffle reduce
        int r = tid >> 3, part = tid & 7;
        float sg = 0.f, sp = 0.f, s0 = 0.f, s1 = 0.f;
#pragma unroll
        for (int i = 0; i < 8; ++i) {
            int c = part * 16 + i * 2;
            f16x2 hv = *(const f16x2*)(tile + swz(r, c * 2));
            float h0 = (float)hv[0], h1 = (float)hv[1];
            sg += h0 * hw[c] + h1 * hw[c + 1];
            sp += h0 * hw[128 + c] + h1 * hw[128 + c + 1];
            s0 += h0 * hw[256 + c * 2] + h1 * hw[256 + (c + 1) * 2];
            s1 += h0 * hw[256 + c * 2 + 1] + h1 * hw[256 + (c + 1) * 2 + 1];
        }
        sg += __shfl_xor(sg, 1); sg += __shfl_xor(sg, 2); sg += __shfl_xor(sg, 4);
        sp += __shfl_xor(sp, 1); sp += __shfl_xor(sp, 2); sp += __shfl_xor(sp, 4);
        s0 += __shfl_xor(s0, 1); s0 += __shfl_xor(s0, 2); s0 += __shfl_xor(s0, 4);
        s1 += __shfl_xor(s1, 1); s1 += __shfl_xor(s1, 2); s1 += __shfl_xor(s1, 4);
        int n = base + r;
        if (part == 0 && n < N_NODES) {
            float g = sg + bg[0];
            out[OUT_GHOST + n]        = 1.f / (1.f + expf(-g));
            out[OUT_PERIOD + n]       = sp + bp[0];
            out[OUT_GRAD + n * 2]     = s0 + br[0];
            out[OUT_GRAD + n * 2 + 1] = s1 + br[1];
        }
        return;
    }

    // GEMM_PQ: wave w -> cols [32w, 32w+32) of 256; fold next-layer b1 into P side
    f32x4 acc2[2][4];
#pragma unroll
    for (int ci = 0; ci < 2; ++ci)
#pragma unroll
        for (int rt = 0; rt < 4; ++rt) acc2[ci][rt] = (f32x4){0.f, 0.f, 0.f, 0.f};
    const f16x8* W1v = (const f16x8*)W1c;
#pragma unroll
    for (int kb = 0; kb < 4; ++kb) {
        f16x8 b0  = W1v[(kb * 16 + 2 * w) * 64 + l];
        f16x8 b1f = W1v[(kb * 16 + 2 * w + 1) * 64 + l];
#pragma unroll
        for (int rt = 0; rt < 4; ++rt) {
            f16x8 a = *(const f16x8*)(tile + swz(rt * 16 + l16, kb * 64 + lg * 16));
            acc2[0][rt] = __builtin_amdgcn_mfma_f32_16x16x32_f16(a, b0,  acc2[0][rt], 0, 0, 0);
            acc2[1][rt] = __builtin_amdgcn_mfma_f32_16x16x32_f16(a, b1f, acc2[1][rt], 0, 0, 0);
        }
    }
#pragma unroll
    for (int ci = 0; ci < 2; ++ci) {
        int col = (2 * w + ci) * 16 + l16;
        float bb = (col < 128) ? b1n[col] : 0.f;
#pragma unroll
        for (int rt = 0; rt < 4; ++rt)
#pragma unroll
            for (int r = 0; r < 4; ++r) {
                int row = rt * 16 + lg * 4 + r;
                if (base + row < N_NODES)
                    PQ[(size_t)(base + row) * 256 + col] = (_Float16)(acc2[ci][rt][r] + bb);
            }
    }
}

// ---------------- encoder (64 rows/block) ----------------
__global__ __launch_bounds__(512, 6)
void node_enc_kernel(const float* __restrict__ x,
                     const float* __restrict__ Wenc, const float* __restrict__ benc,
                     const _Float16* __restrict__ W1c, const float* __restrict__ b1n,
                     _Float16* __restrict__ PQ) {
    __shared__ __align__(16) unsigned char tile[64 * 256];
    const int tid = threadIdx.x;
    const int base = blockIdx.x * 64;

    {
        const int t16 = tid & 15, rg = tid >> 4;
        const int c8 = t16 * 8;
        float wv[4][8], bv[8];
#pragma unroll
        for (int i = 0; i < 4; ++i) {
            float4 a = *(const float4*)&Wenc[i * 128 + c8];
            float4 b = *(const float4*)&Wenc[i * 128 + c8 + 4];
            wv[i][0] = a.x; wv[i][1] = a.y; wv[i][2] = a.z; wv[i][3] = a.w;
            wv[i][4] = b.x; wv[i][5] = b.y; wv[i][6] = b.z; wv[i][7] = b.w;
        }
        float4 ba = *(const float4*)&benc[c8];
        float4 bb = *(const float4*)&benc[c8 + 4];
        bv[0] = ba.x; bv[1] = ba.y; bv[2] = ba.z; bv[3] = ba.w;
        bv[4] = bb.x; bv[5] = bb.y; bv[6] = bb.z; bv[7] = bb.w;
#pragma unroll
        for (int rr = 0; rr < 2; ++rr) {
            int row = rg + 32 * rr;
            float4 xr = {0.f, 0.f, 0.f, 0.f};
            if (base + row < N_NODES) xr = *(const float4*)&x[(size_t)(base + row) * 4];
            f16x8 hv;
#pragma unroll
            for (int j = 0; j < 8; ++j) {
                float v = bv[j] + xr.x * wv[0][j] + xr.y * wv[1][j] + xr.z * wv[2][j] + xr.w * wv[3][j];
                hv[j] = (_Float16)v;
            }
            *(f16x8*)(tile + swz(row, c8 * 2)) = hv;
        }
    }
    __syncthreads();

    const int w = tid >> 6, l = tid & 63, l16 = l & 15, lg = l >> 4;
    f32x4 acc2[2][4];
#pragma unroll
    for (int ci = 0; ci < 2; ++ci)
#pragma unroll
        for (int rt = 0; rt < 4; ++rt) acc2[ci][rt] = (f32x4){0.f, 0.f, 0.f, 0.f};
    const f16x8* W1v = (const f16x8*)W1c;
#pragma unroll
    for (int kb = 0; kb < 4; ++kb) {
        f16x8 b0  = W1v[(kb * 16 + 2 * w) * 64 + l];
        f16x8 b1f = W1v[(kb * 16 + 2 * w + 1) * 64 + l];
#pragma unroll
        for (int rt = 0; rt < 4; ++rt) {
            f16x8 a = *(const f16x8*)(tile + swz(rt * 16 + l16, kb * 64 + lg * 16));
            acc2[0][rt] = __builtin_amdgcn_mfma_f32_16x16x32_f16(a, b0,  acc2[0][rt], 0, 0, 0);
            acc2[1][rt] = __builtin_amdgcn_mfma_f32_16x16x32_f16(a, b1f, acc2[1][rt], 0, 0, 0);
        }
    }
#pragma unroll
    for (int ci = 0; ci < 2; ++ci) {
        int col = (2 * w + ci) * 16 + l16;
        float bb = (col < 128) ? b1n[col] : 0.f;
#pragma unroll
        for (int rt = 0; rt < 4; ++rt)
#pragma unroll
            for (int r = 0; r < 4; ++r) {
                int row = rt * 16 + lg * 4 + r;
                if (base + row < N_NODES)
                    PQ[(size_t)(base + row) * 256 + col] = (_Float16)(acc2[ci][rt][r] + bb);
            }
    }
}

extern "C" void kernel_launch(void* const* d_in, const int* in_sizes, int n_in,
                              void* d_out, int out_size, void* d_ws, size_t ws_size,
                              hipStream_t stream) {
    const float* x     = (const float*)d_in[0];
    const int*   ei    = (const int*)d_in[1];
    const float* ea    = (const float*)d_in[2];
    const float* W_enc = (const float*)d_in[3];
    const float* b_enc = (const float*)d_in[4];
    const float* W1    = (const float*)d_in[5];
    const float* b1    = (const float*)d_in[6];
    const float* W2    = (const float*)d_in[7];
    const float* b2    = (const float*)d_in[8];
    const float* Wg    = (const float*)d_in[9];
    const float* bg    = (const float*)d_in[10];
    const float* Wp    = (const float*)d_in[11];
    const float* bp    = (const float*)d_in[12];
    const float* Wr    = (const float*)d_in[13];
    const float* br    = (const float*)d_in[14];

    float* out = (float*)d_out;

    // ws layout (~58 MB)
    char* ws = (char*)d_ws;
    _Float16*     PQ        = (_Float16*)ws;  ws += (size_t)N_NODES * 256 * 2;   // 25.6 MB
    _Float16*     aggH      = (_Float16*)ws;  ws += (size_t)N_NODES * 128 * 2;   // 12.8 MB
    float*        agg32c    = (float*)ws;     ws += (size_t)EBLK * 128 * 4;      // 2.56 MB
    uint2*        sdPE      = (uint2*)ws;     ws += (size_t)N_EDGES * 8;         // 5.12 MB
    uint2*        packedArr = (uint2*)ws;     ws += (size_t)N_EDGES * 8;         // 5.12 MB
    int*          pArr      = (int*)ws;       ws += (size_t)N_EDGES * 4;         // 2.56 MB
    int*          counts8   = (int*)ws;       ws += (size_t)8 * NC * 4;          // 1.6 MB
    int*          cursorC   = (int*)ws;       ws += (size_t)8 * NC * 4;          // 1.6 MB
    int*          deg       = (int*)ws;       ws += (size_t)NC * 4;
    int*          bslot     = (int*)ws;       ws += (size_t)NC * 4;
    _Float16*     W1c       = (_Float16*)ws;  ws += (size_t)131072 * 2;
    _Float16*     W2p       = (_Float16*)ws;  ws += (size_t)65536 * 2;
    int*          chunkSum  = (int*)ws;       ws += 1024;
    int*          chunkBase = (int*)ws;       ws += 1024;

    hipMemsetAsync(counts8, 0, (size_t)8 * NC * 4, stream);
    hipMemsetAsync(agg32c, 0, (size_t)EBLK * 128 * 4, stream);

    count_kernel<<<N_EDGES / 256, 256, 0, stream>>>(ei, counts8);
    csr_local_kernel<<<NCHUNK, 256, 0, stream>>>(counts8, deg, cursorC, chunkSum, bslot, aggH);
    chunk_scan_kernel<<<1, 256, 0, stream>>>(chunkSum, chunkBase);
    rankA_kernel<<<N_EDGES / 256, 256, 0, stream>>>(ei, ea, chunkBase, cursorC, pArr, packedArr);
    rankB_kernel<<<8 * (N_EDGES / 256), 256, 0, stream>>>(pArr, packedArr, sdPE);

    pack_w_kernel<<<196608 / 256, 256, 0, stream>>>(W1, W2, W1c, W2p);
    bnd_setup_kernel<<<(EBLK + 255) / 256, 256, 0, stream>>>(sdPE, bslot);

    node_enc_kernel<<<NBLK64, 512, 0, stream>>>(x, W_enc, b_enc, W1c, b1, PQ);

    for (int l = 0; l < N_LAYERS; ++l) {
        edge_gather_kernel<<<EBLK, 512, 0, stream>>>(
            PQ, sdPE,
            W1 + (size_t)l * 257 * 128 + 256 * 128,
            aggH, agg32c);
        int nl = (l < 3) ? (l + 1) : 0;
        node_layer_kernel<<<NBLK64, 512, 0, stream>>>(
            aggH, deg, bslot, agg32c,
            W2p + (size_t)l * 16384, b2 + l * HIDDEN,
            W1c + (size_t)nl * 32768, b1 + nl * HIDDEN,
            PQ, out, Wg, bg, Wp, bp, Wr, br,
            (l == N_LAYERS - 1) ? 1 : 0);
    }
}

// Round 11
// 306.784 us; speedup vs baseline: 1.0506x; 1.0101x over previous
//
#include <hip/hip_runtime.h>
#include <hip/hip_fp16.h>

#define N_NODES 50000
#define N_EDGES 640000
#define HIDDEN  128
#define N_LAYERS 4
#define TILE_E  128
#define EBLK    (N_EDGES / TILE_E)   // 5000
#define NCHUNK  196                  // ceil(50000/256)
#define NBLK64  ((N_NODES + 63) / 64)  // 782
#define NC      50048                // padded per-class stride (ints)
#define PSLICE  (N_EDGES / 8)        // 80000
// contiguous zero region: agg32c (EBLK*128*4 B) + counts8 (8*NC*4 B)
#define ZBYTES  ((size_t)EBLK * 128 * 4 + (size_t)8 * NC * 4)   // 4,161,536
#define ZN16    (ZBYTES / 16)                                    // 260,096

#define OUT_GHOST  (N_NODES * HIDDEN)
#define OUT_PERIOD (OUT_GHOST + N_NODES)
#define OUT_GRAD   (OUT_PERIOD + N_NODES)

typedef _Float16 f16x8 __attribute__((ext_vector_type(8)));
typedef _Float16 f16x2 __attribute__((ext_vector_type(2)));
typedef float    f32x4 __attribute__((ext_vector_type(4)));

// LDS tile: rows x 256 bytes, XOR-swizzled (T2): byte ^= ((row&7)<<4).
__device__ __forceinline__ int swz(int row, int colbyte) {
    return (row * 256 + colbyte) ^ ((row & 7) << 4);
}

// ---- edge_index dtype self-detection (int64 LE with ids<2^31 -> odd words 0) ----
__device__ __forceinline__ int ei_is64(const int* __restrict__ ei) {
    return (ei[1] == 0 && ei[3] == 0 && ei[5] == 0) ? 1 : 0;
}
__device__ __forceinline__ int ei_src(const int* __restrict__ ei, int is64, int e) {
    return is64 ? ei[2 * e] : ei[e];
}
__device__ __forceinline__ int ei_dst(const int* __restrict__ ei, int is64, int e) {
    return is64 ? ei[2 * (N_EDGES + e)] : ei[N_EDGES + e];
}

// ---------------- fast zero: grid-stride uint4 fill (replaces slow runtime memset) ----------------
__global__ void zero4_kernel(uint4* __restrict__ p) {
    uint4 z = {0u, 0u, 0u, 0u};
    for (size_t i = blockIdx.x * 256 + threadIdx.x; i < ZN16; i += (size_t)gridDim.x * 256)
        p[i] = z;
}

// ---------------- CSR build: class-privatized histogram ----------------
__global__ void count_kernel(const int* __restrict__ ei, int* __restrict__ counts8) {
    int e = blockIdx.x * 256 + threadIdx.x;
    int cls = blockIdx.x & 7;
    atomicAdd(&counts8[cls * NC + ei_dst(ei, ei_is64(ei), e)], 1);
}

// per-chunk local scan of per-node totals -> per-class cursors with class prefix;
// deg, chunk totals, bslot=-1, zero deg-0 aggH rows.
__global__ void csr_local_kernel(const int* __restrict__ counts8,
                                 int* __restrict__ deg,
                                 int* __restrict__ cursorClass,
                                 int* __restrict__ chunkSum,
                                 int* __restrict__ bslot,
                                 _Float16* __restrict__ aggH) {
    __shared__ int buf[256];
    int t = threadIdx.x, i = blockIdx.x * 256 + t;
    int c8[8]; int v = 0;
#pragma unroll
    for (int c = 0; c < 8; ++c) {
        c8[c] = (i < N_NODES) ? counts8[c * NC + i] : 0;
        v += c8[c];
    }
    buf[t] = v;
    __syncthreads();
    for (int off = 1; off < 256; off <<= 1) {
        int add = (t >= off) ? buf[t - off] : 0;
        __syncthreads();
        buf[t] += add;
        __syncthreads();
    }
    if (i < N_NODES) {
        int run = buf[t] - v;   // chunk-local exclusive prefix
#pragma unroll
        for (int c = 0; c < 8; ++c) { cursorClass[c * NC + i] = run; run += c8[c]; }
        deg[i] = v;
        bslot[i] = -1;
        if (v == 0) {
            float4 z = {0.f, 0.f, 0.f, 0.f};
#pragma unroll
            for (int k = 0; k < 16; ++k)
                *(float4*)&aggH[(size_t)i * 128 + k * 8] = z;
        }
    }
    if (t == 255) chunkSum[blockIdx.x] = buf[255];
}

__global__ void chunk_scan_kernel(const int* __restrict__ chunkSum, int* __restrict__ chunkBase) {
    __shared__ int buf[256];
    int t = threadIdx.x;
    int v = (t < NCHUNK) ? chunkSum[t] : 0;
    buf[t] = v;
    __syncthreads();
    for (int off = 1; off < 256; off <<= 1) {
        int add = (t >= off) ? buf[t - off] : 0;
        __syncthreads();
        buf[t] += add;
        __syncthreads();
    }
    if (t < NCHUNK) chunkBase[t] = buf[t] - v;
}

// phase A: rank each edge (class-private atomics), write p + packed payload COALESCED
__global__ void rankA_kernel(const int* __restrict__ ei, const float* __restrict__ ea,
                             const int* __restrict__ chunkBase, int* __restrict__ cursorClass,
                             int* __restrict__ pArr, uint2* __restrict__ packedArr) {
    int e = blockIdx.x * 256 + threadIdx.x;
    int cls = blockIdx.x & 7;
    int is64 = ei_is64(ei);
    int s = ei_src(ei, is64, e);
    int d = ei_dst(ei, is64, e);
    int p = chunkBase[d >> 8] + atomicAdd(&cursorClass[cls * NC + d], 1);
    pArr[e] = p;
    uint2 v;
    v.x = (unsigned)s | ((unsigned)d << 16);   // N_NODES < 65536
    v.y = __float_as_uint(ea[e]);
    packedArr[e] = v;
}

// phase B: 8 p-range replicas permute payload into sorted stream (XCD-local lines)
__global__ void rankB_kernel(const int* __restrict__ pArr, const uint2* __restrict__ packedArr,
                             uint2* __restrict__ sdPE) {
    int r = blockIdx.x & 7;
    int e = (blockIdx.x >> 3) * 256 + threadIdx.x;
    int p = pArr[e];
    if ((unsigned)p / PSLICE == (unsigned)r) sdPE[p] = packedArr[e];
}

// ---------------- weight pre-pack into MFMA fragment order (f16) ----------------
__global__ void pack_w_kernel(const float* __restrict__ W1, const float* __restrict__ W2,
                              _Float16* __restrict__ W1c, _Float16* __restrict__ W2p) {
    int id = blockIdx.x * 256 + threadIdx.x;
    if (id < 131072) {
        int j = id & 7, l = (id >> 3) & 63, c = (id >> 9) & 15, kb = (id >> 13) & 3, lay = id >> 15;
        int k = kb * 32 + (l >> 4) * 8 + j, col = c * 16 + (l & 15);
        const float* Wl = W1 + (size_t)lay * 257 * 128;
        W1c[id] = (_Float16)((col < 128) ? Wl[(size_t)k * 128 + col]
                                         : Wl[(size_t)(128 + k) * 128 + (col - 128)]);
    } else if (id < 196608) {
        int id2 = id - 131072;
        int j = id2 & 7, l = (id2 >> 3) & 63, c = (id2 >> 9) & 7, kb = (id2 >> 12) & 3, lay = id2 >> 14;
        int k = kb * 32 + (l >> 4) * 8 + j, col = c * 16 + (l & 15);
        W2p[id2] = (_Float16)W2[(size_t)lay * 128 * 128 + (size_t)k * 128 + col];
    }
}

// ---------------- boundary slots (valid while max degree < TILE_E) ----------------
__global__ void bnd_setup_kernel(const uint2* __restrict__ sdPE, int* __restrict__ bslot) {
    int t = blockIdx.x * 256 + threadIdx.x;
    if (t >= 1 && t < EBLK) {
        unsigned dp = sdPE[t * TILE_E - 1].x >> 16;
        unsigned d0 = sdPE[t * TILE_E].x >> 16;
        if (dp == d0) bslot[d0] = t;
    }
}

// ---------------- edge kernel: gather P'[dst]+Q[src] -> hidden -> segment-sum ----------------
// P' has b1 pre-folded; hidden = relu(P' + Q + ea*w1last). Round-7 proven structure.
__global__ __launch_bounds__(512, 8)
void edge_gather_kernel(const _Float16* __restrict__ PQ,
                        const uint2* __restrict__ sdPE,
                        const float* __restrict__ w1last,
                        _Float16* __restrict__ aggH, float* __restrict__ agg32c) {
    __shared__ __align__(16) unsigned char tile[TILE_E * 256];
    __shared__ int dstL[TILE_E];
    __shared__ int srcL[TILE_E];
    __shared__ _Float16 eaL[TILE_E];
    __shared__ int segStart[TILE_E + 1];
    __shared__ int nsegS, contP, contN;

    const int tid = threadIdx.x;
    const int bid = (blockIdx.x & 7) * (EBLK / 8) + (blockIdx.x >> 3);  // XCD swizzle
    const int e_base = bid * TILE_E;

    // P0: coalesced packed-index load -> LDS
    if (tid < TILE_E) {
        uint2 u = sdPE[e_base + tid];
        srcL[tid] = (int)(u.x & 0xFFFFu);
        dstL[tid] = (int)(u.x >> 16);
        eaL[tid]  = (_Float16)__uint_as_float(u.y);
    } else if (tid == TILE_E) {
        contP = (e_base > 0 && (sdPE[e_base - 1].x >> 16) == (sdPE[e_base].x >> 16)) ? 1 : 0;
    } else if (tid == TILE_E + 1) {
        contN = (e_base + TILE_E < N_EDGES &&
                 (sdPE[e_base + TILE_E - 1].x >> 16) == (sdPE[e_base + TILE_E].x >> 16)) ? 1 : 0;
    }
    __syncthreads();

    // segment ranks (waves 0,1)
    if (tid < 128) {
        int lane = tid & 63;
        int fl_lo = (lane == 0) ? 1 : (dstL[lane] != dstL[lane - 1]);
        unsigned long long m0 = __ballot(fl_lo);
        if (tid < 64) {
            if (fl_lo) segStart[__popcll(m0 & ((1ull << lane) - 1))] = lane;
        } else {
            int j = 64 + lane;
            int fl = (dstL[j] != dstL[j - 1]);
            unsigned long long m1 = __ballot(fl);
            int nlo = __popcll(m0);
            if (fl) segStart[nlo + __popcll(m1 & ((1ull << lane) - 1))] = j;
            if (lane == 0) {
                int ns = nlo + __popcll(m1);
                nsegS = ns;
                segStart[ns] = TILE_E;
            }
        }
    }

    // P1: preload gathers, packed-f16 hidden = relu(P' + Q + ea*wl)
    {
        const int t16 = tid & 15, rg = tid >> 4;
        const int c8 = t16 * 8;

        f16x8 pv[4], qv[4];
#pragma unroll
        for (int rr = 0; rr < 4; ++rr) {
            int row = rg + 32 * rr;
            pv[rr] = *(const f16x8*)&PQ[(size_t)dstL[row] * 256 + c8];
            qv[rr] = *(const f16x8*)&PQ[(size_t)srcL[row] * 256 + 128 + c8];
        }

        f16x8 wl8, z8;
#pragma unroll
        for (int j = 0; j < 8; ++j) {
            wl8[j] = (_Float16)w1last[c8 + j];
            z8[j]  = (_Float16)0.f;
        }

#pragma unroll
        for (int rr = 0; rr < 4; ++rr) {
            int row = rg + 32 * rr;
            f16x8 t = pv[rr] + qv[rr] + wl8 * eaL[row];
            f16x8 hv = __builtin_elementwise_max(t, z8);
            *(f16x8*)(tile + swz(row, c8 * 2)) = hv;
        }
    }
    __syncthreads();

    // P2: per-segment column sums; interior -> f16 store, boundary -> slot atomics
    {
        int col2 = (tid & 63) * 2, sh = tid >> 6;
        int ns = nsegS, cP = contP, cN = contN;
        for (int s = sh; s < ns; s += 8) {
            int b = segStart[s], en = segStart[s + 1];
            float s0 = 0.f, s1 = 0.f;
            for (int e2 = b; e2 < en; ++e2) {
                f16x2 hv = *(const f16x2*)(tile + swz(e2, col2 * 2));
                s0 += (float)hv[0];
                s1 += (float)hv[1];
            }
            bool isP = (s == 0 && cP), isN = (s == ns - 1 && cN);
            if (isP || isN) {
                int slot = isP ? bid : bid + 1;
                atomicAdd(&agg32c[(size_t)slot * 128 + col2], s0);
                atomicAdd(&agg32c[(size_t)slot * 128 + col2 + 1], s1);
            } else {
                int node = dstL[b];
                f16x2 o; o[0] = (_Float16)s0; o[1] = (_Float16)s1;
                *(f16x2*)&aggH[(size_t)node * 128 + col2] = o;
            }
        }
    }
}

// ---------------- node kernel (64 rows/block, 8 waves) ----------------
__global__ __launch_bounds__(512, 6)
void node_layer_kernel(const _Float16* __restrict__ aggH,
                       const int* __restrict__ deg,
                       const int* __restrict__ bslot, float* __restrict__ agg32c,
                       const _Float16* __restrict__ W2p, const float* __restrict__ b2,
                       const _Float16* __restrict__ W1c, const float* __restrict__ b1n,
                       _Float16* __restrict__ PQ, float* __restrict__ out,
                       const float* __restrict__ Wg, const float* __restrict__ bg,
                       const float* __restrict__ Wp, const float* __restrict__ bp,
                       const float* __restrict__ Wr, const float* __restrict__ br,
                       int last) {
    __shared__ __align__(16) unsigned char tile[64 * 256];
    __shared__ int degL[64];
    __shared__ float hw[512];

    const int tid = threadIdx.x;
    const int base = blockIdx.x * 64;

    {
        const int t16 = tid & 15, rg = tid >> 4;
#pragma unroll
        for (int rr = 0; rr < 2; ++rr) {
            int row = rg + 32 * rr;
            int n = base + row;
            f16x8 v = {0, 0, 0, 0, 0, 0, 0, 0};
            if (n < N_NODES) {
                int bs = bslot[n];
                if (bs >= 0) {
                    float* ap = &agg32c[(size_t)bs * 128 + t16 * 8];
                    float4 a = *(const float4*)ap;
                    float4 b = *(const float4*)(ap + 4);
                    v[0] = (_Float16)a.x; v[1] = (_Float16)a.y;
                    v[2] = (_Float16)a.z; v[3] = (_Float16)a.w;
                    v[4] = (_Float16)b.x; v[5] = (_Float16)b.y;
                    v[6] = (_Float16)b.z; v[7] = (_Float16)b.w;
                    float4 z = {0.f, 0.f, 0.f, 0.f};   // re-zero for next layer
                    *(float4*)ap = z; *(float4*)(ap + 4) = z;
                } else {
                    v = *(const f16x8*)&aggH[(size_t)n * 128 + t16 * 8];
                }
            }
            *(f16x8*)(tile + swz(row, t16 * 16)) = v;
        }
        if (tid < 64) degL[tid] = (base + tid < N_NODES) ? deg[base + tid] : 0;
        if (last) {
            if (tid < 128)       hw[tid] = Wg[tid];
            else if (tid < 256)  hw[tid] = Wp[tid - 128];
            else                 hw[tid] = Wr[tid - 256];
        }
    }
    __syncthreads();

    const int w = tid >> 6, l = tid & 63, l16 = l & 15, lg = l >> 4;

    // GEMM_h: wave w -> h cols [16w, 16w+16)
    f32x4 acc[4];
#pragma unroll
    for (int rt = 0; rt < 4; ++rt) acc[rt] = (f32x4){0.f, 0.f, 0.f, 0.f};
    const f16x8* W2v = (const f16x8*)W2p;
#pragma unroll
    for (int kb = 0; kb < 4; ++kb) {
        f16x8 bf = W2v[(kb * 8 + w) * 64 + l];
#pragma unroll
        for (int rt = 0; rt < 4; ++rt) {
            f16x8 a = *(const f16x8*)(tile + swz(rt * 16 + l16, kb * 64 + lg * 16));
            acc[rt] = __builtin_amdgcn_mfma_f32_16x16x32_f16(a, bf, acc[rt], 0, 0, 0);
        }
    }
    __syncthreads();   // all A-reads done before h overwrites tile

    {
        int col = 16 * w + l16;
        float bias = b2[col];
#pragma unroll
        for (int rt = 0; rt < 4; ++rt)
#pragma unroll
            for (int r = 0; r < 4; ++r) {
                int row = rt * 16 + lg * 4 + r;
                float h = fmaxf(acc[rt][r] + (float)degL[row] * bias, 0.f);
                *(_Float16*)(tile + swz(row, col * 2)) = (_Float16)h;
                if (last && base + row < N_NODES)
                    out[(size_t)(base + row) * 128 + col] = h;
            }
    }
    __syncthreads();

    if (last) {
        // fused heads: 8 threads/node, 16 cols each, 3-level shuffle reduce
        int r = tid >> 3, part = tid & 7;
        float sg = 0.f, sp = 0.f, s0 = 0.f, s1 = 0.f;
#pragma unroll
        for (int i = 0; i < 8; ++i) {
            int c = part * 16 + i * 2;
            f16x2 hv = *(const f16x2*)(tile + swz(r, c * 2));
            float h0 = (float)hv[0], h1 = (float)hv[1];
            sg += h0 * hw[c] + h1 * hw[c + 1];
            sp += h0 * hw[128 + c] + h1 * hw[128 + c + 1];
            s0 += h0 * hw[256 + c * 2] + h1 * hw[256 + (c + 1) * 2];
            s1 += h0 * hw[256 + c * 2 + 1] + h1 * hw[256 + (c + 1) * 2 + 1];
        }
        sg += __shfl_xor(sg, 1); sg += __shfl_xor(sg, 2); sg += __shfl_xor(sg, 4);
        sp += __shfl_xor(sp, 1); sp += __shfl_xor(sp, 2); sp += __shfl_xor(sp, 4);
        s0 += __shfl_xor(s0, 1); s0 += __shfl_xor(s0, 2); s0 += __shfl_xor(s0, 4);
        s1 += __shfl_xor(s1, 1); s1 += __shfl_xor(s1, 2); s1 += __shfl_xor(s1, 4);
        int n = base + r;
        if (part == 0 && n < N_NODES) {
            float g = sg + bg[0];
            out[OUT_GHOST + n]        = 1.f / (1.f + expf(-g));
            out[OUT_PERIOD + n]       = sp + bp[0];
            out[OUT_GRAD + n * 2]     = s0 + br[0];
            out[OUT_GRAD + n * 2 + 1] = s1 + br[1];
        }
        return;
    }

    // GEMM_PQ: wave w -> cols [32w, 32w+32) of 256; fold next-layer b1 into P side
    f32x4 acc2[2][4];
#pragma unroll
    for (int ci = 0; ci < 2; ++ci)
#pragma unroll
        for (int rt = 0; rt < 4; ++rt) acc2[ci][rt] = (f32x4){0.f, 0.f, 0.f, 0.f};
    const f16x8* W1v = (const f16x8*)W1c;
#pragma unroll
    for (int kb = 0; kb < 4; ++kb) {
        f16x8 b0  = W1v[(kb * 16 + 2 * w) * 64 + l];
        f16x8 b1f = W1v[(kb * 16 + 2 * w + 1) * 64 + l];
#pragma unroll
        for (int rt = 0; rt < 4; ++rt) {
            f16x8 a = *(const f16x8*)(tile + swz(rt * 16 + l16, kb * 64 + lg * 16));
            acc2[0][rt] = __builtin_amdgcn_mfma_f32_16x16x32_f16(a, b0,  acc2[0][rt], 0, 0, 0);
            acc2[1][rt] = __builtin_amdgcn_mfma_f32_16x16x32_f16(a, b1f, acc2[1][rt], 0, 0, 0);
        }
    }
#pragma unroll
    for (int ci = 0; ci < 2; ++ci) {
        int col = (2 * w + ci) * 16 + l16;
        float bb = (col < 128) ? b1n[col] : 0.f;
#pragma unroll
        for (int rt = 0; rt < 4; ++rt)
#pragma unroll
            for (int r = 0; r < 4; ++r) {
                int row = rt * 16 + lg * 4 + r;
                if (base + row < N_NODES)
                    PQ[(size_t)(base + row) * 256 + col] = (_Float16)(acc2[ci][rt][r] + bb);
            }
    }
}

// ---------------- encoder (64 rows/block) ----------------
__global__ __launch_bounds__(512, 6)
void node_enc_kernel(const float* __restrict__ x,
                     const float* __restrict__ Wenc, const float* __restrict__ benc,
                     const _Float16* __restrict__ W1c, const float* __restrict__ b1n,
                     _Float16* __restrict__ PQ) {
    __shared__ __align__(16) unsigned char tile[64 * 256];
    const int tid = threadIdx.x;
    const int base = blockIdx.x * 64;

    {
        const int t16 = tid & 15, rg = tid >> 4;
        const int c8 = t16 * 8;
        float wv[4][8], bv[8];
#pragma unroll
        for (int i = 0; i < 4; ++i) {
            float4 a = *(const float4*)&Wenc[i * 128 + c8];
            float4 b = *(const float4*)&Wenc[i * 128 + c8 + 4];
            wv[i][0] = a.x; wv[i][1] = a.y; wv[i][2] = a.z; wv[i][3] = a.w;
            wv[i][4] = b.x; wv[i][5] = b.y; wv[i][6] = b.z; wv[i][7] = b.w;
        }
        float4 ba = *(const float4*)&benc[c8];
        float4 bb = *(const float4*)&benc[c8 + 4];
        bv[0] = ba.x; bv[1] = ba.y; bv[2] = ba.z; bv[3] = ba.w;
        bv[4] = bb.x; bv[5] = bb.y; bv[6] = bb.z; bv[7] = bb.w;
#pragma unroll
        for (int rr = 0; rr < 2; ++rr) {
            int row = rg + 32 * rr;
            float4 xr = {0.f, 0.f, 0.f, 0.f};
            if (base + row < N_NODES) xr = *(const float4*)&x[(size_t)(base + row) * 4];
            f16x8 hv;
#pragma unroll
            for (int j = 0; j < 8; ++j) {
                float v = bv[j] + xr.x * wv[0][j] + xr.y * wv[1][j] + xr.z * wv[2][j] + xr.w * wv[3][j];
                hv[j] = (_Float16)v;
            }
            *(f16x8*)(tile + swz(row, c8 * 2)) = hv;
        }
    }
    __syncthreads();

    const int w = tid >> 6, l = tid & 63, l16 = l & 15, lg = l >> 4;
    f32x4 acc2[2][4];
#pragma unroll
    for (int ci = 0; ci < 2; ++ci)
#pragma unroll
        for (int rt = 0; rt < 4; ++rt) acc2[ci][rt] = (f32x4){0.f, 0.f, 0.f, 0.f};
    const f16x8* W1v = (const f16x8*)W1c;
#pragma unroll
    for (int kb = 0; kb < 4; ++kb) {
        f16x8 b0  = W1v[(kb * 16 + 2 * w) * 64 + l];
        f16x8 b1f = W1v[(kb * 16 + 2 * w + 1) * 64 + l];
#pragma unroll
        for (int rt = 0; rt < 4; ++rt) {
            f16x8 a = *(const f16x8*)(tile + swz(rt * 16 + l16, kb * 64 + lg * 16));
            acc2[0][rt] = __builtin_amdgcn_mfma_f32_16x16x32_f16(a, b0,  acc2[0][rt], 0, 0, 0);
            acc2[1][rt] = __builtin_amdgcn_mfma_f32_16x16x32_f16(a, b1f, acc2[1][rt], 0, 0, 0);
        }
    }
#pragma unroll
    for (int ci = 0; ci < 2; ++ci) {
        int col = (2 * w + ci) * 16 + l16;
        float bb = (col < 128) ? b1n[col] : 0.f;
#pragma unroll
        for (int rt = 0; rt < 4; ++rt)
#pragma unroll
            for (int r = 0; r < 4; ++r) {
                int row = rt * 16 + lg * 4 + r;
                if (base + row < N_NODES)
                    PQ[(size_t)(base + row) * 256 + col] = (_Float16)(acc2[ci][rt][r] + bb);
            }
    }
}

extern "C" void kernel_launch(void* const* d_in, const int* in_sizes, int n_in,
                              void* d_out, int out_size, void* d_ws, size_t ws_size,
                              hipStream_t stream) {
    const float* x     = (const float*)d_in[0];
    const int*   ei    = (const int*)d_in[1];
    const float* ea    = (const float*)d_in[2];
    const float* W_enc = (const float*)d_in[3];
    const float* b_enc = (const float*)d_in[4];
    const float* W1    = (const float*)d_in[5];
    const float* b1    = (const float*)d_in[6];
    const float* W2    = (const float*)d_in[7];
    const float* b2    = (const float*)d_in[8];
    const float* Wg    = (const float*)d_in[9];
    const float* bg    = (const float*)d_in[10];
    const float* Wp    = (const float*)d_in[11];
    const float* bp    = (const float*)d_in[12];
    const float* Wr    = (const float*)d_in[13];
    const float* br    = (const float*)d_in[14];

    float* out = (float*)d_out;

    // ws layout (~58 MB); agg32c + counts8 ADJACENT -> single fast zero region
    char* ws = (char*)d_ws;
    _Float16*     PQ        = (_Float16*)ws;  ws += (size_t)N_NODES * 256 * 2;   // 25.6 MB
    _Float16*     aggH      = (_Float16*)ws;  ws += (size_t)N_NODES * 128 * 2;   // 12.8 MB
    float*        agg32c    = (float*)ws;     ws += (size_t)EBLK * 128 * 4;      // 2.56 MB  \ zeroed
    int*          counts8   = (int*)ws;       ws += (size_t)8 * NC * 4;          // 1.6 MB   / together
    uint2*        sdPE      = (uint2*)ws;     ws += (size_t)N_EDGES * 8;         // 5.12 MB
    uint2*        packedArr = (uint2*)ws;     ws += (size_t)N_EDGES * 8;         // 5.12 MB
    int*          pArr      = (int*)ws;       ws += (size_t)N_EDGES * 4;         // 2.56 MB
    int*          cursorC   = (int*)ws;       ws += (size_t)8 * NC * 4;          // 1.6 MB
    int*          deg       = (int*)ws;       ws += (size_t)NC * 4;
    int*          bslot     = (int*)ws;       ws += (size_t)NC * 4;
    _Float16*     W1c       = (_Float16*)ws;  ws += (size_t)131072 * 2;
    _Float16*     W2p       = (_Float16*)ws;  ws += (size_t)65536 * 2;
    int*          chunkSum  = (int*)ws;       ws += 1024;
    int*          chunkBase = (int*)ws;       ws += 1024;

    // fast zero of agg32c + counts8 (replaces 2 slow runtime memsets, ~75 us -> ~3 us)
    zero4_kernel<<<512, 256, 0, stream>>>((uint4*)agg32c);

    count_kernel<<<N_EDGES / 256, 256, 0, stream>>>(ei, counts8);
    csr_local_kernel<<<NCHUNK, 256, 0, stream>>>(counts8, deg, cursorC, chunkSum, bslot, aggH);
    chunk_scan_kernel<<<1, 256, 0, stream>>>(chunkSum, chunkBase);
    rankA_kernel<<<N_EDGES / 256, 256, 0, stream>>>(ei, ea, chunkBase, cursorC, pArr, packedArr);
    rankB_kernel<<<8 * (N_EDGES / 256), 256, 0, stream>>>(pArr, packedArr, sdPE);

    pack_w_kernel<<<196608 / 256, 256, 0, stream>>>(W1, W2, W1c, W2p);
    bnd_setup_kernel<<<(EBLK + 255) / 256, 256, 0, stream>>>(sdPE, bslot);

    node_enc_kernel<<<NBLK64, 512, 0, stream>>>(x, W_enc, b_enc, W1c, b1, PQ);

    for (int l = 0; l < N_LAYERS; ++l) {
        edge_gather_kernel<<<EBLK, 512, 0, stream>>>(
            PQ, sdPE,
            W1 + (size_t)l * 257 * 128 + 256 * 128,
            aggH, agg32c);
        int nl = (l < 3) ? (l + 1) : 0;
        node_layer_kernel<<<NBLK64, 512, 0, stream>>>(
            aggH, deg, bslot, agg32c,
            W2p + (size_t)l * 16384, b2 + l * HIDDEN,
            W1c + (size_t)nl * 32768, b1 + nl * HIDDEN,
            PQ, out, Wg, bg, Wp, bp, Wr, br,
            (l == N_LAYERS - 1) ? 1 : 0);
    }
}